// Round 7
// baseline (737.068 us; speedup 1.0000x reference)
//
#include <hip/hip_runtime.h>
#include <cstdint>
#include <cstddef>

using u16 = unsigned short;
using u32 = unsigned int;

// ---------------- helpers ----------------
__device__ __forceinline__ float bf2f(u16 u){
  union { u32 i; float f; } x; x.i = ((u32)u) << 16; return x.f;
}
__device__ __forceinline__ u16 f2bf(float f){
  union { float f; u32 i; } x; x.f = f;
  u32 r = x.i + 0x7fffu + ((x.i >> 16) & 1u);
  return (u16)(r >> 16);
}
__device__ __forceinline__ float gelu_f(float x){
  return 0.5f * x * (1.0f + erff(x * 0.70710678118654752f));
}
__device__ __forceinline__ void gld16(const void* g, void* l){
  // async global->LDS, 16B/lane; LDS dst = wave-uniform base + lane*16; global src per-lane
  __builtin_amdgcn_global_load_lds((__attribute__((address_space(1))) void*)(void*)g,
                                   (__attribute__((address_space(3))) void*)l, 16, 0, 0);
}

typedef __bf16 bf16x8 __attribute__((ext_vector_type(8)));
typedef float  f32x4  __attribute__((ext_vector_type(4)));
typedef u16    u16x4  __attribute__((ext_vector_type(4)));

// ---------------- weight transpose + cast: src fp32 [R,C] -> dst bf16 [C,R] ----------------
__global__ __launch_bounds__(256) void k_transpose(const float* __restrict__ src,
                                                   u16* __restrict__ dst, int R, int C){
  __shared__ u16 tile[32][33];
  int bx = blockIdx.x * 32;
  int by = blockIdx.y * 32;
  int tx = threadIdx.x & 31;
  int ty = threadIdx.x >> 5;
  for (int r = ty; r < 32; r += 8)
    tile[r][tx] = f2bf(src[(size_t)(by + r) * C + bx + tx]);
  __syncthreads();
  for (int r = ty; r < 32; r += 8)
    dst[(size_t)(bx + r) * R + by + tx] = tile[tx][r];
}

// ---------------- layernorm over last dim (cols = 1024 or 512), optional gelu, bf16 out ----------------
template<bool IN_F32, bool DO_GELU>
__global__ __launch_bounds__(256) void k_layernorm(const void* __restrict__ inp,
    const float* __restrict__ w, const float* __restrict__ bsh,
    u16* __restrict__ out, int cols, float eps){
  int row = blockIdx.x, t = threadIdx.x;
  size_t base = (size_t)row * cols;
  const float* inf = (const float*)inp;
  const u16*  inb = (const u16*)inp;
  float v[4];
  int ep = cols >> 8;
  float s = 0.f, ss = 0.f;
  for (int e = 0; e < ep; ++e){
    int idx = t + (e << 8);
    float x = IN_F32 ? inf[base + idx] : bf2f(inb[base + idx]);
    v[e] = x; s += x; ss += x * x;
  }
#pragma unroll
  for (int off = 1; off < 64; off <<= 1){
    s  += __shfl_xor(s, off, 64);
    ss += __shfl_xor(ss, off, 64);
  }
  __shared__ float red[8];
  int wv = t >> 6;
  if ((t & 63) == 0){ red[wv] = s; red[4 + wv] = ss; }
  __syncthreads();
  s  = red[0] + red[1] + red[2] + red[3];
  ss = red[4] + red[5] + red[6] + red[7];
  float inv = 1.f / (float)cols;
  float mean = s * inv;
  float var = ss * inv - mean * mean;
  float rs = rsqrtf(var + eps);
  for (int e = 0; e < ep; ++e){
    int idx = t + (e << 8);
    float y = (v[e] - mean) * rs * w[idx] + bsh[idx];
    if (DO_GELU) y = gelu_f(y);
    out[base + idx] = f2bf(y);
  }
}

// ---------------- final: out(fp32) = x2(bf16) + LN(c3; ln3) , cols=1024 ----------------
__global__ __launch_bounds__(256) void k_final(const u16* __restrict__ c3,
    const u16* __restrict__ x2, const float* __restrict__ w,
    const float* __restrict__ bsh, float* __restrict__ out){
  int row = blockIdx.x, t = threadIdx.x;
  size_t base = (size_t)row << 10;
  float v[4];
  float s = 0.f, ss = 0.f;
#pragma unroll
  for (int e = 0; e < 4; ++e){
    int idx = t + (e << 8);
    float x = bf2f(c3[base + idx]);
    v[e] = x; s += x; ss += x * x;
  }
#pragma unroll
  for (int off = 1; off < 64; off <<= 1){
    s  += __shfl_xor(s, off, 64);
    ss += __shfl_xor(ss, off, 64);
  }
  __shared__ float red[8];
  int wv = t >> 6;
  if ((t & 63) == 0){ red[wv] = s; red[4 + wv] = ss; }
  __syncthreads();
  s  = red[0] + red[1] + red[2] + red[3];
  ss = red[4] + red[5] + red[6] + red[7];
  float mean = s * (1.f/1024.f);
  float var = ss * (1.f/1024.f) - mean * mean;
  float rs = rsqrtf(var + 1e-6f);
#pragma unroll
  for (int e = 0; e < 4; ++e){
    int idx = t + (e << 8);
    float y = (v[e] - mean) * rs * w[idx] + bsh[idx];
    out[base + idx] = bf2f(x2[base + idx]) + y;
  }
}

// ---------------- MFMA GEMM: C[M,N] = A[M,K](bf16) * Bt[N,K]^T(bf16) (+fp32 bias/res, gelu) ----------------
// 128x128 tile, BK=32, 4 waves. 3-deep LDS pipeline with COUNTED vmcnt (T4, m218):
// stage tile k+2, wait vmcnt(8) (tile k landed; k+1,k+2 stay in flight), barrier,
// compute tile k, barrier. Loads get ~2 phases to land; never drain to 0 in the loop.
// XCD-aware bijective block swizzle (T1/m204).
template<bool BIAS, bool GELU, bool RES, bool OUTB, bool OUTF>
__global__ __launch_bounds__(256, 2) void k_gemm(
    const u16* __restrict__ A, const u16* __restrict__ Bt,
    const float* __restrict__ bias, const float* __restrict__ resf,
    u16* __restrict__ outb, float* __restrict__ outf, int N, int K)
{
  __shared__ __align__(16) u16 As[3][128 * 32];
  __shared__ __align__(16) u16 Bs[3][128 * 32];
  int t = threadIdx.x, lane = t & 63, wv = t >> 6;

  int nbx = gridDim.x;
  int nwg = nbx * gridDim.y;
  int li  = blockIdx.y * nbx + blockIdx.x;
  int qc = nwg >> 3, rc = nwg & 7;
  int xcd = li & 7, jj = li >> 3;
  int wg = (xcd < rc ? xcd * (qc + 1) : rc * (qc + 1) + (xcd - rc) * qc) + jj;
  int byy = wg / nbx;
  int bxx = wg - byy * nbx;
  int m0 = byy << 7, n0 = bxx << 7;

  int wm = (wv >> 1) << 6, wn = (wv & 1) << 6;

  f32x4 acc[4][4];
  const f32x4 z4 = {0.f, 0.f, 0.f, 0.f};
#pragma unroll
  for (int i = 0; i < 4; ++i)
#pragma unroll
    for (int j = 0; j < 4; ++j) acc[i][j] = z4;

  int srow = (wv << 5) + (lane >> 2);
  int skp  = (lane & 3) << 3;
  const u16* Ag = A  + (size_t)(m0 + srow) * K + skp;
  const u16* Bg = Bt + (size_t)(n0 + srow) * K + skp;
  const size_t rowskip = (size_t)16 * K;

  int fr = lane & 15, fq = (lane >> 4) << 3;

#define G_STAGE(buf, k0) { \
    u16* a0 = &As[buf][(wv << 5) * 32]; \
    u16* b0 = &Bs[buf][(wv << 5) * 32]; \
    gld16(Ag + (k0), a0); \
    gld16(Ag + rowskip + (k0), a0 + 16 * 32); \
    gld16(Bg + (k0), b0); \
    gld16(Bg + rowskip + (k0), b0 + 16 * 32); }

#define G_COMPUTE(buf) { \
    bf16x8 af[4], bfr[4]; \
    _Pragma("unroll") \
    for (int i = 0; i < 4; ++i) \
      af[i] = *(const bf16x8*)&As[buf][(wm + i * 16 + fr) * 32 + fq]; \
    _Pragma("unroll") \
    for (int j = 0; j < 4; ++j) \
      bfr[j] = *(const bf16x8*)&Bs[buf][(wn + j * 16 + fr) * 32 + fq]; \
    _Pragma("unroll") \
    for (int i = 0; i < 4; ++i) \
      _Pragma("unroll") \
      for (int j = 0; j < 4; ++j) \
        acc[i][j] = __builtin_amdgcn_mfma_f32_16x16x32_bf16(af[i], bfr[j], acc[i][j], 0, 0, 0); }

  int nk = K >> 5;                 // >= 16 for all call sites
  // prologue: two tiles in flight
  G_STAGE(0, 0);
  G_STAGE(1, 32);

  for (int kk = 0; kk < nk; ++kk){
    int nxt = kk + 2;
    if (nxt < nk){
      int bn = nxt % 3;
      G_STAGE(bn, nxt << 5);
      asm volatile("s_waitcnt vmcnt(8)" ::: "memory");   // tile kk landed; 2 tiles in flight
    } else if (kk + 1 < nk){
      asm volatile("s_waitcnt vmcnt(4)" ::: "memory");   // tile kk landed; 1 tile in flight
    } else {
      asm volatile("s_waitcnt vmcnt(0)" ::: "memory");   // last tile
    }
    __builtin_amdgcn_s_barrier();                        // all waves' tile-kk stores visible
    int bc = kk % 3;
    G_COMPUTE(bc);
    // ds_reads drained via MFMA data-deps before this barrier; buffer bc is only
    // re-staged (as tile kk+3) after all waves pass it.
    __builtin_amdgcn_s_barrier();
  }

#undef G_STAGE
#undef G_COMPUTE

  int rr = (lane >> 4) << 2;
  int cc = lane & 15;
#pragma unroll
  for (int i = 0; i < 4; ++i)
#pragma unroll
    for (int j = 0; j < 4; ++j){
      int gc = n0 + wn + j * 16 + cc;
      float bb = BIAS ? bias[gc] : 0.f;
#pragma unroll
      for (int r = 0; r < 4; ++r){
        int gr = m0 + wm + i * 16 + rr + r;
        size_t idx = (size_t)gr * N + gc;
        float vv = acc[i][j][r] + bb;
        if (RES) vv += resf[idx];
        if (GELU) vv = gelu_f(vv);
        if (OUTF) outf[idx] = vv;
        if (OUTB) outb[idx] = f2bf(vv);
      }
    }
}

// ---------------- V pre-transpose: qkvbuf V slice -> vtg[bnh][64 d][832 j] (bf16, j zero-padded) ----------------
__global__ __launch_bounds__(256) void k_vtrans(const u16* __restrict__ qkv, u16* __restrict__ vtg){
  __shared__ u32 tile[64][33];
  int bnh = blockIdx.x;            // 0..127
  int st  = blockIdx.y;            // 0..12
  int b = bnh >> 4, nh = bnh & 15;
  int t = threadIdx.x;
  int tx = t & 31;                 // dword column (2 u16)
  int ty = t >> 5;                 // 0..7
  const u16* src = qkv + (size_t)b * 784 * 3072 + 2048 + nh * 64;
  int s0 = st << 6;
  for (int r = ty; r < 64; r += 8){
    int s = s0 + r;
    u32 val = 0u;
    if (s < 784) val = *(const u32*)(src + (size_t)s * 3072 + tx * 2);
    tile[r][tx] = val;
  }
  __syncthreads();
  u16* dst = vtg + (size_t)bnh * 64 * 832 + s0;
  for (int d = ty; d < 64; d += 8){
    u32 lo = tile[2 * tx][d >> 1];
    u32 hi = tile[2 * tx + 1][d >> 1];
    u16 a  = (d & 1) ? (u16)(lo >> 16) : (u16)lo;
    u16 bb = (d & 1) ? (u16)(hi >> 16) : (u16)hi;
    u32 pk = (u32)a | ((u32)bb << 16);
    *(u32*)(dst + (size_t)d * 832 + 2 * tx) = pk;
  }
}

// ---------------- MFMA flash attention v7: coalesced LDS staging + XOR swizzle ----------------
#define PST 72
#define GSTR 132
#define LOG2E 1.4426950408889634f
__global__ __launch_bounds__(256, 3) void k_attn7(const u16* __restrict__ qkv,
    const float* __restrict__ relh, const float* __restrict__ relw,
    const u16* __restrict__ vtg, u16* __restrict__ out)
{
  __shared__ __align__(16) u16 k_s[64 * 64];        // 8 KB, swizzled K tile (row j, col d)
  __shared__ __align__(16) u16 v_s[64 * 64];        // 8 KB, swizzled V^T tile (row d, col j)
  __shared__ __align__(16) u16 p_s[128 * PST];      // 18.4 KB, P; also Rh/Rw staging
  __shared__ __align__(16) u16 gh_t[28 * GSTR];     // 7.4 KB, transposed bias (x log2e)
  __shared__ __align__(16) u16 gw_t[28 * GSTR];     // 7.4 KB

  const int t = threadIdx.x, lane = t & 63, wv = t >> 6;
  int id = blockIdx.x;
  int xr = id & 7, rest = id >> 3;
  int qt = rest % 7, gg = rest / 7;
  int bnh = xr + (gg << 3);
  const int b = bnh >> 4, nh = bnh & 15;
  const int q0 = qt << 7;
  const size_t rowbase = (size_t)b * 784;
  const int wq0 = wv << 5;
  const int fr = lane & 15;
  const int fq = lane >> 4;

  // stage Rh/Rw (bf16) into p_s region
  u16* rh_s = p_s;
  u16* rw_s = p_s + 64 * PST;
  {
    int row = t >> 2, c0 = (t & 3) << 4;
    u16 bh_[16], bw_[16];
    if (row < 55){
      const float* ph = relh + row * 64 + c0;
      const float* pw = relw + row * 64 + c0;
#pragma unroll
      for (int e = 0; e < 16; ++e){ bh_[e] = f2bf(ph[e]); bw_[e] = f2bf(pw[e]); }
    } else {
#pragma unroll
      for (int e = 0; e < 16; ++e){ bh_[e] = 0; bw_[e] = 0; }
    }
    *(uint4*)&rh_s[row * PST + c0]     = *(uint4*)bh_;
    *(uint4*)&rh_s[row * PST + c0 + 8] = *(uint4*)(bh_ + 8);
    *(uint4*)&rw_s[row * PST + c0]     = *(uint4*)bw_;
    *(uint4*)&rw_s[row * PST + c0 + 8] = *(uint4*)(bw_ + 8);
  }

  // Q fragments (registers)
  bf16x8 qf[2][2];
#pragma unroll
  for (int mf = 0; mf < 2; ++mf)
#pragma unroll
    for (int ks = 0; ks < 2; ++ks){
      int row = q0 + wq0 + mf * 16 + fr;
      if (row < 784){
        qf[mf][ks] = *(const bf16x8*)(qkv + (rowbase + row) * 3072 + nh * 64 + fq * 8 + ks * 32);
      } else {
        uint4 z = {0u,0u,0u,0u}; qf[mf][ks] = *(bf16x8*)&z;
      }
    }
  __syncthreads();

  const f32x4 z4 = {0.f,0.f,0.f,0.f};
  // ---- decomposed rel-pos bias via MFMA -> transposed tables gt[kk][lr], pre-scaled by log2e ----
#pragma unroll
  for (int which = 0; which < 2; ++which){
    const u16* rs = which ? rw_s : rh_s;
    f32x4 G[2][4];
#pragma unroll
    for (int mf = 0; mf < 2; ++mf)
#pragma unroll
      for (int nf = 0; nf < 4; ++nf) G[mf][nf] = z4;
#pragma unroll
    for (int nf = 0; nf < 4; ++nf){
      bf16x8 rf0 = *(const bf16x8*)&rs[(nf * 16 + fr) * PST + fq * 8];
      bf16x8 rf1 = *(const bf16x8*)&rs[(nf * 16 + fr) * PST + fq * 8 + 32];
#pragma unroll
      for (int mf = 0; mf < 2; ++mf){
        G[mf][nf] = __builtin_amdgcn_mfma_f32_16x16x32_bf16(qf[mf][0], rf0, G[mf][nf], 0, 0, 0);
        G[mf][nf] = __builtin_amdgcn_mfma_f32_16x16x32_bf16(qf[mf][1], rf1, G[mf][nf], 0, 0, 0);
      }
    }
    u16* gt = which ? gw_t : gh_t;
#pragma unroll
    for (int mf = 0; mf < 2; ++mf)
#pragma unroll
      for (int r = 0; r < 4; ++r){
        int lr = wq0 + mf * 16 + fq * 4 + r;
        int grow = q0 + lr;
        int hq = grow / 28;
        int coord = which ? (grow - hq * 28) : hq;
#pragma unroll
        for (int nf = 0; nf < 4; ++nf){
          int j = nf * 16 + fr;
          int kk = coord + 27 - j;
          if ((unsigned)kk < 28u) gt[kk * GSTR + lr] = f2bf(G[mf][nf][r] * LOG2E);
        }
      }
  }
  __syncthreads();   // tables + Rh/Rw reads complete before p_s reuse / k_s staging

  f32x4 acc[2][5];
#pragma unroll
  for (int mf = 0; mf < 2; ++mf)
#pragma unroll
    for (int nf = 0; nf < 5; ++nf) acc[mf][nf] = z4;

  u16 onesu[8];
#pragma unroll
  for (int e = 0; e < 8; ++e) onesu[e] = 0x3f80;
  bf16x8 onesf = *(bf16x8*)onesu;

  // staging decomposition: lane -> (sub-row sr, swizzled 16B slot sc)
  const int sr = lane >> 3;                 // 0..7
  const int sc = (lane & 7) ^ sr;           // pre-swizzled source slot (involution)
  const u16* kstage = qkv + rowbase * 3072 + 1024 + nh * 64;       // + row*3072 + sc*8
  const u16* vstage = vtg + (size_t)bnh * 64 * 832;                // + d*832 + ktb + sc*8
  const int r0 = (wv << 4) + sr;            // this wave stages rows [wv*16, wv*16+16)
  u16* kd0 = &k_s[(wv << 4) * 64];
  u16* kd1 = &k_s[((wv << 4) + 8) * 64];
  u16* vd0 = &v_s[(wv << 4) * 64];
  u16* vd1 = &v_s[((wv << 4) + 8) * 64];
  const int swz = (fr & 7);                 // fragment-read swizzle key

  const float SSC = 0.125f * LOG2E;

  for (int kt = 0; kt < 13; ++kt){
    const int ktb = kt << 6;
    __syncthreads();                        // WAR: previous tile fully consumed
    {
      int jg0 = ktb + r0;       int jc0 = jg0 < 784 ? jg0 : 783;
      int jg1 = jg0 + 8;        int jc1 = jg1 < 784 ? jg1 : 783;
      gld16(kstage + (size_t)jc0 * 3072 + (sc << 3), kd0);
      gld16(kstage + (size_t)jc1 * 3072 + (sc << 3), kd1);
      gld16(vstage + (size_t)r0 * 832 + ktb + (sc << 3), vd0);
      gld16(vstage + (size_t)(r0 + 8) * 832 + ktb + (sc << 3), vd1);
    }
    __syncthreads();                        // staging visible (implicit vmcnt drain)

    // QK^T from swizzled LDS
    f32x4 S[2][4];
#pragma unroll
    for (int nf = 0; nf < 4; ++nf){
      int rb = (nf * 16 + fr) << 6;
      bf16x8 kf0 = *(const bf16x8*)&k_s[rb + ((fq ^ swz) << 3)];
      bf16x8 kf1 = *(const bf16x8*)&k_s[rb + (((fq + 4) ^ swz) << 3)];
#pragma unroll
      for (int mf = 0; mf < 2; ++mf){
        f32x4 s = z4;
        s = __builtin_amdgcn_mfma_f32_16x16x32_bf16(qf[mf][0], kf0, s, 0, 0, 0);
        s = __builtin_amdgcn_mfma_f32_16x16x32_bf16(qf[mf][1], kf1, s, 0, 0, 0);
        S[mf][nf] = s;
      }
    }

    int hj[4], wj[4]; bool val[4];
#pragma unroll
    for (int nf = 0; nf < 4; ++nf){
      int jg = ktb + nf * 16 + fr;
      int h = jg / 28;
      hj[nf] = h; wj[nf] = jg - h * 28; val[nf] = (jg < 784);
    }

    // p = exp2(SSC*S + bias2); bias via b64 reads of transposed tables
#pragma unroll
    for (int mf = 0; mf < 2; ++mf){
      int lrb = wq0 + mf * 16 + fq * 4;
#pragma unroll
      for (int nf = 0; nf < 4; ++nf){
        u16x4 h4 = *(const u16x4*)&gh_t[hj[nf] * GSTR + lrb];
        u16x4 w4 = *(const u16x4*)&gw_t[wj[nf] * GSTR + lrb];
#pragma unroll
        for (int r = 0; r < 4; ++r){
          float p = 0.f;
          if (val[nf])
            p = exp2f(fmaf(SSC, S[mf][nf][r], bf2f(h4[r]) + bf2f(w4[r])));
          p_s[(lrb + r) * PST + nf * 16 + fr] = f2bf(p);
        }
      }
    }

    // PV: P from wave-private LDS rows, V^T fragments from swizzled LDS
#pragma unroll
    for (int ks = 0; ks < 2; ++ks){
      bf16x8 pf0 = *(const bf16x8*)&p_s[(wq0 + fr) * PST + fq * 8 + ks * 32];
      bf16x8 pf1 = *(const bf16x8*)&p_s[(wq0 + 16 + fr) * PST + fq * 8 + ks * 32];
#pragma unroll
      for (int nf = 0; nf < 4; ++nf){
        bf16x8 vf = *(const bf16x8*)&v_s[((nf * 16 + fr) << 6) + (((fq + ks * 4) ^ swz) << 3)];
        acc[0][nf] = __builtin_amdgcn_mfma_f32_16x16x32_bf16(pf0, vf, acc[0][nf], 0, 0, 0);
        acc[1][nf] = __builtin_amdgcn_mfma_f32_16x16x32_bf16(pf1, vf, acc[1][nf], 0, 0, 0);
      }
      acc[0][4] = __builtin_amdgcn_mfma_f32_16x16x32_bf16(pf0, onesf, acc[0][4], 0, 0, 0);
      acc[1][4] = __builtin_amdgcn_mfma_f32_16x16x32_bf16(pf1, onesf, acc[1][4], 0, 0, 0);
    }
  }

#pragma unroll
  for (int mf = 0; mf < 2; ++mf)
#pragma unroll
    for (int r = 0; r < 4; ++r){
      int row = q0 + wq0 + mf * 16 + fq * 4 + r;
      if (row < 784){
        float inv = 1.f / acc[mf][4][r];   // ones-fragment: every column holds the row sum
        u16* dp = out + (rowbase + row) * 1024 + nh * 64 + fr;
#pragma unroll
        for (int nf = 0; nf < 4; ++nf)
          dp[nf * 16] = f2bf(acc[mf][nf][r] * inv);
      }
    }
}

// ---------------- im2col for 3x3 pad-1 conv: g[B,28,28,512](bf16) -> im[6272, 4608] ----------------
__global__ __launch_bounds__(256) void k_im2col(const u16* __restrict__ g, u16* __restrict__ im){
  int idx = blockIdx.x * 256 + threadIdx.x;
  int p  = idx / 576;
  int c8 = idx - p * 576;
  int k0 = c8 << 3;
  int t9 = k0 >> 9;
  int ci = k0 & 511;
  int ky = t9 / 3, kx = t9 - ky * 3;
  int bb = p / 784;
  int s = p - bb * 784;
  int h = s / 28, w = s - h * 28;
  int hh = h + ky - 1, ww = w + kx - 1;
  uint4 val = make_uint4(0u, 0u, 0u, 0u);
  if ((unsigned)hh < 28u && (unsigned)ww < 28u)
    val = *(const uint4*)&g[(((size_t)(bb * 28 + hh)) * 28 + ww) * 512 + ci];
  *(uint4*)&im[(size_t)p * 4608 + k0] = val;
}

// ---------------- orchestration ----------------
extern "C" void kernel_launch(void* const* d_in, const int* in_sizes, int n_in,
                              void* d_out, int out_size, void* d_ws, size_t ws_size,
                              hipStream_t stream)
{
  (void)in_sizes; (void)n_in; (void)out_size; (void)ws_size;
  const float* x      = (const float*)d_in[0];
  const float* n1w    = (const float*)d_in[1];
  const float* n1b    = (const float*)d_in[2];
  const float* qkv_w  = (const float*)d_in[3];
  const float* qkv_b  = (const float*)d_in[4];
  const float* proj_w = (const float*)d_in[5];
  const float* proj_b = (const float*)d_in[6];
  const float* rel_h  = (const float*)d_in[7];
  const float* rel_w  = (const float*)d_in[8];
  const float* n2w    = (const float*)d_in[9];
  const float* n2b    = (const float*)d_in[10];
  const float* fc1_w  = (const float*)d_in[11];
  const float* fc1_b  = (const float*)d_in[12];
  const float* fc2_w  = (const float*)d_in[13];
  const float* fc2_b  = (const float*)d_in[14];
  const float* c1w    = (const float*)d_in[15];
  const float* l1w    = (const float*)d_in[16];
  const float* l1b    = (const float*)d_in[17];
  const float* c2w    = (const float*)d_in[18];
  const float* l2w    = (const float*)d_in[19];
  const float* l2b    = (const float*)d_in[20];
  const float* c3w    = (const float*)d_in[21];
  const float* l3w    = (const float*)d_in[22];
  const float* l3b    = (const float*)d_in[23];

  char* ws = (char*)d_ws;
  size_t off = 0;
  auto alloc = [&](size_t bytes) -> void* {
    void* p = ws + off; off += (bytes + 255) & ~(size_t)255; return p;
  };
  const size_t M = 6272;
  u16* qkvT  = (u16*)alloc((size_t)3072 * 1024 * 2);
  u16* projT = (u16*)alloc((size_t)1024 * 1024 * 2);
  u16* fc1T  = (u16*)alloc((size_t)4096 * 1024 * 2);
  u16* fc2T  = (u16*)alloc((size_t)1024 * 4096 * 2);
  u16* c1T   = (u16*)alloc((size_t)512 * 1024 * 2);
  u16* c2T   = (u16*)alloc((size_t)512 * 4608 * 2);
  u16* c3T   = (u16*)alloc((size_t)1024 * 512 * 2);
  u16* qkvbuf = (u16*)alloc(M * 3072 * 2);
  u16* attn   = (u16*)alloc(M * 1024 * 2);
  u16* xn     = (u16*)alloc(M * 1024 * 2);
  float* x1   = (float*)alloc(M * 1024 * 4);
  u16* x2b    = (u16*)alloc(M * 1024 * 2);
  u16* c1buf  = (u16*)alloc(M * 512 * 2);
  u16* g1buf  = (u16*)alloc(M * 512 * 2);
  u16* hmlp   = qkvbuf;
  u16* im     = qkvbuf;
  u16* xn2    = xn;
  u16* c2buf  = c1buf;
  u16* g2buf  = g1buf;
  u16* c3buf  = attn;
  // vtg (13.6 MB) aliases x1 (25.7 MB): x1 is dead until the proj GEMM, which runs after attn.
  u16* vtg    = (u16*)x1;

  dim3 blk(256);
  k_transpose<<<dim3(3072/32, 1024/32), blk, 0, stream>>>(qkv_w, qkvT, 1024, 3072);
  k_transpose<<<dim3(1024/32, 1024/32), blk, 0, stream>>>(proj_w, projT, 1024, 1024);
  k_transpose<<<dim3(4096/32, 1024/32), blk, 0, stream>>>(fc1_w, fc1T, 1024, 4096);
  k_transpose<<<dim3(1024/32, 4096/32), blk, 0, stream>>>(fc2_w, fc2T, 4096, 1024);
  k_transpose<<<dim3(512/32, 1024/32),  blk, 0, stream>>>(c1w, c1T, 1024, 512);
  k_transpose<<<dim3(512/32, 4608/32),  blk, 0, stream>>>(c2w, c2T, 4608, 512);
  k_transpose<<<dim3(1024/32, 512/32),  blk, 0, stream>>>(c3w, c3T, 512, 1024);

  k_layernorm<true,false><<<6272, blk, 0, stream>>>(x, n1w, n1b, xn, 1024, 1e-5f);
  k_gemm<true,false,false,true,false><<<dim3(24,49), blk, 0, stream>>>(
      xn, qkvT, qkv_b, nullptr, qkvbuf, nullptr, 3072, 1024);
  k_vtrans<<<dim3(128, 13), blk, 0, stream>>>(qkvbuf, vtg);
  k_attn7<<<896, blk, 0, stream>>>(qkvbuf, rel_h, rel_w, vtg, attn);
  k_gemm<true,false,true,false,true><<<dim3(8,49), blk, 0, stream>>>(
      attn, projT, proj_b, x, nullptr, x1, 1024, 1024);
  k_layernorm<true,false><<<6272, blk, 0, stream>>>(x1, n2w, n2b, xn2, 1024, 1e-5f);
  k_gemm<true,true,false,true,false><<<dim3(32,49), blk, 0, stream>>>(
      xn2, fc1T, fc1_b, nullptr, hmlp, nullptr, 4096, 1024);
  k_gemm<true,false,true,true,false><<<dim3(8,49), blk, 0, stream>>>(
      hmlp, fc2T, fc2_b, x1, x2b, nullptr, 1024, 4096);
  k_gemm<false,false,false,true,false><<<dim3(4,49), blk, 0, stream>>>(
      x2b, c1T, nullptr, nullptr, c1buf, nullptr, 512, 1024);
  k_layernorm<false,true><<<6272, blk, 0, stream>>>(c1buf, l1w, l1b, g1buf, 512, 1e-6f);
  k_im2col<<<14112, blk, 0, stream>>>(g1buf, im);
  k_gemm<false,false,false,true,false><<<dim3(4,49), blk, 0, stream>>>(
      im, c2T, nullptr, nullptr, c2buf, nullptr, 512, 4608);
  k_layernorm<false,true><<<6272, blk, 0, stream>>>(c2buf, l2w, l2b, g2buf, 512, 1e-6f);
  k_gemm<false,false,false,true,false><<<dim3(8,49), blk, 0, stream>>>(
      g2buf, c3T, nullptr, nullptr, c3buf, nullptr, 1024, 512);
  k_final<<<6272, blk, 0, stream>>>(c3buf, x2b, l3w, l3b, (float*)d_out);
}

// Round 8
// 729.111 us; speedup vs baseline: 1.0109x; 1.0109x over previous
//
#include <hip/hip_runtime.h>
#include <cstdint>
#include <cstddef>

using u16 = unsigned short;
using u32 = unsigned int;

// ---------------- helpers ----------------
__device__ __forceinline__ float bf2f(u16 u){
  union { u32 i; float f; } x; x.i = ((u32)u) << 16; return x.f;
}
__device__ __forceinline__ u16 f2bf(float f){
  union { float f; u32 i; } x; x.f = f;
  u32 r = x.i + 0x7fffu + ((x.i >> 16) & 1u);
  return (u16)(r >> 16);
}
__device__ __forceinline__ float gelu_f(float x){
  return 0.5f * x * (1.0f + erff(x * 0.70710678118654752f));
}
__device__ __forceinline__ void gld16(const void* g, void* l){
  // async global->LDS, 16B/lane; LDS dst = wave-uniform base + lane*16; global src per-lane
  __builtin_amdgcn_global_load_lds((__attribute__((address_space(1))) void*)(void*)g,
                                   (__attribute__((address_space(3))) void*)l, 16, 0, 0);
}

typedef __bf16 bf16x8 __attribute__((ext_vector_type(8)));
typedef float  f32x4  __attribute__((ext_vector_type(4)));
typedef u16    u16x4  __attribute__((ext_vector_type(4)));

// ---------------- weight transpose + cast: src fp32 [R,C] -> dst bf16 [C,R] ----------------
__global__ __launch_bounds__(256) void k_transpose(const float* __restrict__ src,
                                                   u16* __restrict__ dst, int R, int C){
  __shared__ u16 tile[32][33];
  int bx = blockIdx.x * 32;
  int by = blockIdx.y * 32;
  int tx = threadIdx.x & 31;
  int ty = threadIdx.x >> 5;
  for (int r = ty; r < 32; r += 8)
    tile[r][tx] = f2bf(src[(size_t)(by + r) * C + bx + tx]);
  __syncthreads();
  for (int r = ty; r < 32; r += 8)
    dst[(size_t)(bx + r) * R + by + tx] = tile[tx][r];
}

// ---------------- layernorm over last dim (cols = 1024 or 512), optional gelu, bf16 out ----------------
template<bool IN_F32, bool DO_GELU>
__global__ __launch_bounds__(256) void k_layernorm(const void* __restrict__ inp,
    const float* __restrict__ w, const float* __restrict__ bsh,
    u16* __restrict__ out, int cols, float eps){
  int row = blockIdx.x, t = threadIdx.x;
  size_t base = (size_t)row * cols;
  const float* inf = (const float*)inp;
  const u16*  inb = (const u16*)inp;
  float v[4];
  int ep = cols >> 8;
  float s = 0.f, ss = 0.f;
  for (int e = 0; e < ep; ++e){
    int idx = t + (e << 8);
    float x = IN_F32 ? inf[base + idx] : bf2f(inb[base + idx]);
    v[e] = x; s += x; ss += x * x;
  }
#pragma unroll
  for (int off = 1; off < 64; off <<= 1){
    s  += __shfl_xor(s, off, 64);
    ss += __shfl_xor(ss, off, 64);
  }
  __shared__ float red[8];
  int wv = t >> 6;
  if ((t & 63) == 0){ red[wv] = s; red[4 + wv] = ss; }
  __syncthreads();
  s  = red[0] + red[1] + red[2] + red[3];
  ss = red[4] + red[5] + red[6] + red[7];
  float inv = 1.f / (float)cols;
  float mean = s * inv;
  float var = ss * inv - mean * mean;
  float rs = rsqrtf(var + eps);
  for (int e = 0; e < ep; ++e){
    int idx = t + (e << 8);
    float y = (v[e] - mean) * rs * w[idx] + bsh[idx];
    if (DO_GELU) y = gelu_f(y);
    out[base + idx] = f2bf(y);
  }
}

// ---------------- final: out(fp32) = x2(bf16) + LN(c3; ln3) , cols=1024 ----------------
__global__ __launch_bounds__(256) void k_final(const u16* __restrict__ c3,
    const u16* __restrict__ x2, const float* __restrict__ w,
    const float* __restrict__ bsh, float* __restrict__ out){
  int row = blockIdx.x, t = threadIdx.x;
  size_t base = (size_t)row << 10;
  float v[4];
  float s = 0.f, ss = 0.f;
#pragma unroll
  for (int e = 0; e < 4; ++e){
    int idx = t + (e << 8);
    float x = bf2f(c3[base + idx]);
    v[e] = x; s += x; ss += x * x;
  }
#pragma unroll
  for (int off = 1; off < 64; off <<= 1){
    s  += __shfl_xor(s, off, 64);
    ss += __shfl_xor(ss, off, 64);
  }
  __shared__ float red[8];
  int wv = t >> 6;
  if ((t & 63) == 0){ red[wv] = s; red[4 + wv] = ss; }
  __syncthreads();
  s  = red[0] + red[1] + red[2] + red[3];
  ss = red[4] + red[5] + red[6] + red[7];
  float mean = s * (1.f/1024.f);
  float var = ss * (1.f/1024.f) - mean * mean;
  float rs = rsqrtf(var + 1e-6f);
#pragma unroll
  for (int e = 0; e < 4; ++e){
    int idx = t + (e << 8);
    float y = (v[e] - mean) * rs * w[idx] + bsh[idx];
    out[base + idx] = bf2f(x2[base + idx]) + y;
  }
}

// ---------------- MFMA GEMM: C[M,N] = A[M,K](bf16) * Bt[N,K]^T(bf16) (+fp32 bias/res, gelu) ----------------
// 128x128 tile, BK=32, 4 waves. DEPTH-deep LDS pipeline with COUNTED vmcnt (T4, m218):
// DEPTH=3 (48KB) for low-TLP grids (<2 blocks/CU): 2 tiles in flight, vmcnt(8).
// DEPTH=2 (32KB) for high-TLP grids: 1 tile in flight, vmcnt(4) — keeps 5 blocks/CU.
// Never drain vmcnt to 0 inside the loop. XCD-aware bijective block swizzle (T1/m204).
template<int DEPTH, bool BIAS, bool GELU, bool RES, bool OUTB, bool OUTF>
__global__ __launch_bounds__(256, 2) void k_gemm(
    const u16* __restrict__ A, const u16* __restrict__ Bt,
    const float* __restrict__ bias, const float* __restrict__ resf,
    u16* __restrict__ outb, float* __restrict__ outf, int N, int K)
{
  __shared__ __align__(16) u16 As[DEPTH][128 * 32];
  __shared__ __align__(16) u16 Bs[DEPTH][128 * 32];
  int t = threadIdx.x, lane = t & 63, wv = t >> 6;

  int nbx = gridDim.x;
  int nwg = nbx * gridDim.y;
  int li  = blockIdx.y * nbx + blockIdx.x;
  int qc = nwg >> 3, rc = nwg & 7;
  int xcd = li & 7, jj = li >> 3;
  int wg = (xcd < rc ? xcd * (qc + 1) : rc * (qc + 1) + (xcd - rc) * qc) + jj;
  int byy = wg / nbx;
  int bxx = wg - byy * nbx;
  int m0 = byy << 7, n0 = bxx << 7;

  int wm = (wv >> 1) << 6, wn = (wv & 1) << 6;

  f32x4 acc[4][4];
  const f32x4 z4 = {0.f, 0.f, 0.f, 0.f};
#pragma unroll
  for (int i = 0; i < 4; ++i)
#pragma unroll
    for (int j = 0; j < 4; ++j) acc[i][j] = z4;

  int srow = (wv << 5) + (lane >> 2);
  int skp  = (lane & 3) << 3;
  const u16* Ag = A  + (size_t)(m0 + srow) * K + skp;
  const u16* Bg = Bt + (size_t)(n0 + srow) * K + skp;
  const size_t rowskip = (size_t)16 * K;

  int fr = lane & 15, fq = (lane >> 4) << 3;

#define G_STAGE(buf, k0) { \
    u16* a0 = &As[buf][(wv << 5) * 32]; \
    u16* b0 = &Bs[buf][(wv << 5) * 32]; \
    gld16(Ag + (k0), a0); \
    gld16(Ag + rowskip + (k0), a0 + 16 * 32); \
    gld16(Bg + (k0), b0); \
    gld16(Bg + rowskip + (k0), b0 + 16 * 32); }

#define G_COMPUTE(buf) { \
    bf16x8 af[4], bfr[4]; \
    _Pragma("unroll") \
    for (int i = 0; i < 4; ++i) \
      af[i] = *(const bf16x8*)&As[buf][(wm + i * 16 + fr) * 32 + fq]; \
    _Pragma("unroll") \
    for (int j = 0; j < 4; ++j) \
      bfr[j] = *(const bf16x8*)&Bs[buf][(wn + j * 16 + fr) * 32 + fq]; \
    _Pragma("unroll") \
    for (int i = 0; i < 4; ++i) \
      _Pragma("unroll") \
      for (int j = 0; j < 4; ++j) \
        acc[i][j] = __builtin_amdgcn_mfma_f32_16x16x32_bf16(af[i], bfr[j], acc[i][j], 0, 0, 0); }

  int nk = K >> 5;                 // >= 32 for all call sites
  // prologue: DEPTH-1 tiles in flight
  G_STAGE(0, 0);
  if (DEPTH == 3) G_STAGE(1, 32);

  for (int kk = 0; kk < nk; ++kk){
    int nxt = kk + (DEPTH - 1);
    if (nxt < nk){
      G_STAGE(nxt % DEPTH, nxt << 5);
      if (DEPTH == 3) asm volatile("s_waitcnt vmcnt(8)" ::: "memory");  // tile kk landed; 2 in flight
      else            asm volatile("s_waitcnt vmcnt(4)" ::: "memory");  // tile kk landed; 1 in flight
    } else if (DEPTH == 3 && kk + 1 < nk){
      asm volatile("s_waitcnt vmcnt(4)" ::: "memory");
    } else {
      asm volatile("s_waitcnt vmcnt(0)" ::: "memory");
    }
    __builtin_amdgcn_s_barrier();                        // all waves' tile-kk stores visible
    G_COMPUTE(kk % DEPTH);
    // ds_reads drained via MFMA data-deps before this barrier; buffer kk%DEPTH is only
    // re-staged (as tile kk+DEPTH) after all waves pass it.
    __builtin_amdgcn_s_barrier();
  }

#undef G_STAGE
#undef G_COMPUTE

  int rr = (lane >> 4) << 2;
  int cc = lane & 15;
#pragma unroll
  for (int i = 0; i < 4; ++i)
#pragma unroll
    for (int j = 0; j < 4; ++j){
      int gc = n0 + wn + j * 16 + cc;
      float bb = BIAS ? bias[gc] : 0.f;
#pragma unroll
      for (int r = 0; r < 4; ++r){
        int gr = m0 + wm + i * 16 + rr + r;
        size_t idx = (size_t)gr * N + gc;
        float vv = acc[i][j][r] + bb;
        if (RES) vv += resf[idx];
        if (GELU) vv = gelu_f(vv);
        if (OUTF) outf[idx] = vv;
        if (OUTB) outb[idx] = f2bf(vv);
      }
    }
}

// ---------------- V pre-transpose: qkvbuf V slice -> vtg[bnh][64 d][832 j] (bf16, j zero-padded) ----------------
__global__ __launch_bounds__(256) void k_vtrans(const u16* __restrict__ qkv, u16* __restrict__ vtg){
  __shared__ u32 tile[64][33];
  int bnh = blockIdx.x;            // 0..127
  int st  = blockIdx.y;            // 0..12
  int b = bnh >> 4, nh = bnh & 15;
  int t = threadIdx.x;
  int tx = t & 31;                 // dword column (2 u16)
  int ty = t >> 5;                 // 0..7
  const u16* src = qkv + (size_t)b * 784 * 3072 + 2048 + nh * 64;
  int s0 = st << 6;
  for (int r = ty; r < 64; r += 8){
    int s = s0 + r;
    u32 val = 0u;
    if (s < 784) val = *(const u32*)(src + (size_t)s * 3072 + tx * 2);
    tile[r][tx] = val;
  }
  __syncthreads();
  u16* dst = vtg + (size_t)bnh * 64 * 832 + s0;
  for (int d = ty; d < 64; d += 8){
    u32 lo = tile[2 * tx][d >> 1];
    u32 hi = tile[2 * tx + 1][d >> 1];
    u16 a  = (d & 1) ? (u16)(lo >> 16) : (u16)lo;
    u16 bb = (d & 1) ? (u16)(hi >> 16) : (u16)hi;
    u32 pk = (u32)a | ((u32)bb << 16);
    *(u32*)(dst + (size_t)d * 832 + 2 * tx) = pk;
  }
}

// ---------------- MFMA flash attention v7: coalesced LDS staging + XOR swizzle ----------------
#define PST 72
#define GSTR 132
#define LOG2E 1.4426950408889634f
__global__ __launch_bounds__(256, 3) void k_attn7(const u16* __restrict__ qkv,
    const float* __restrict__ relh, const float* __restrict__ relw,
    const u16* __restrict__ vtg, u16* __restrict__ out)
{
  __shared__ __align__(16) u16 k_s[64 * 64];        // 8 KB, swizzled K tile (row j, col d)
  __shared__ __align__(16) u16 v_s[64 * 64];        // 8 KB, swizzled V^T tile (row d, col j)
  __shared__ __align__(16) u16 p_s[128 * PST];      // 18.4 KB, P; also Rh/Rw staging
  __shared__ __align__(16) u16 gh_t[28 * GSTR];     // 7.4 KB, transposed bias (x log2e)
  __shared__ __align__(16) u16 gw_t[28 * GSTR];     // 7.4 KB

  const int t = threadIdx.x, lane = t & 63, wv = t >> 6;
  int id = blockIdx.x;
  int xr = id & 7, rest = id >> 3;
  int qt = rest % 7, gg = rest / 7;
  int bnh = xr + (gg << 3);
  const int b = bnh >> 4, nh = bnh & 15;
  const int q0 = qt << 7;
  const size_t rowbase = (size_t)b * 784;
  const int wq0 = wv << 5;
  const int fr = lane & 15;
  const int fq = lane >> 4;

  // stage Rh/Rw (bf16) into p_s region
  u16* rh_s = p_s;
  u16* rw_s = p_s + 64 * PST;
  {
    int row = t >> 2, c0 = (t & 3) << 4;
    u16 bh_[16], bw_[16];
    if (row < 55){
      const float* ph = relh + row * 64 + c0;
      const float* pw = relw + row * 64 + c0;
#pragma unroll
      for (int e = 0; e < 16; ++e){ bh_[e] = f2bf(ph[e]); bw_[e] = f2bf(pw[e]); }
    } else {
#pragma unroll
      for (int e = 0; e < 16; ++e){ bh_[e] = 0; bw_[e] = 0; }
    }
    *(uint4*)&rh_s[row * PST + c0]     = *(uint4*)bh_;
    *(uint4*)&rh_s[row * PST + c0 + 8] = *(uint4*)(bh_ + 8);
    *(uint4*)&rw_s[row * PST + c0]     = *(uint4*)bw_;
    *(uint4*)&rw_s[row * PST + c0 + 8] = *(uint4*)(bw_ + 8);
  }

  // Q fragments (registers)
  bf16x8 qf[2][2];
#pragma unroll
  for (int mf = 0; mf < 2; ++mf)
#pragma unroll
    for (int ks = 0; ks < 2; ++ks){
      int row = q0 + wq0 + mf * 16 + fr;
      if (row < 784){
        qf[mf][ks] = *(const bf16x8*)(qkv + (rowbase + row) * 3072 + nh * 64 + fq * 8 + ks * 32);
      } else {
        uint4 z = {0u,0u,0u,0u}; qf[mf][ks] = *(bf16x8*)&z;
      }
    }
  __syncthreads();

  const f32x4 z4 = {0.f,0.f,0.f,0.f};
  // ---- decomposed rel-pos bias via MFMA -> transposed tables gt[kk][lr], pre-scaled by log2e ----
#pragma unroll
  for (int which = 0; which < 2; ++which){
    const u16* rs = which ? rw_s : rh_s;
    f32x4 G[2][4];
#pragma unroll
    for (int mf = 0; mf < 2; ++mf)
#pragma unroll
      for (int nf = 0; nf < 4; ++nf) G[mf][nf] = z4;
#pragma unroll
    for (int nf = 0; nf < 4; ++nf){
      bf16x8 rf0 = *(const bf16x8*)&rs[(nf * 16 + fr) * PST + fq * 8];
      bf16x8 rf1 = *(const bf16x8*)&rs[(nf * 16 + fr) * PST + fq * 8 + 32];
#pragma unroll
      for (int mf = 0; mf < 2; ++mf){
        G[mf][nf] = __builtin_amdgcn_mfma_f32_16x16x32_bf16(qf[mf][0], rf0, G[mf][nf], 0, 0, 0);
        G[mf][nf] = __builtin_amdgcn_mfma_f32_16x16x32_bf16(qf[mf][1], rf1, G[mf][nf], 0, 0, 0);
      }
    }
    u16* gt = which ? gw_t : gh_t;
#pragma unroll
    for (int mf = 0; mf < 2; ++mf)
#pragma unroll
      for (int r = 0; r < 4; ++r){
        int lr = wq0 + mf * 16 + fq * 4 + r;
        int grow = q0 + lr;
        int hq = grow / 28;
        int coord = which ? (grow - hq * 28) : hq;
#pragma unroll
        for (int nf = 0; nf < 4; ++nf){
          int j = nf * 16 + fr;
          int kk = coord + 27 - j;
          if ((unsigned)kk < 28u) gt[kk * GSTR + lr] = f2bf(G[mf][nf][r] * LOG2E);
        }
      }
  }
  __syncthreads();   // tables + Rh/Rw reads complete before p_s reuse / k_s staging

  f32x4 acc[2][5];
#pragma unroll
  for (int mf = 0; mf < 2; ++mf)
#pragma unroll
    for (int nf = 0; nf < 5; ++nf) acc[mf][nf] = z4;

  u16 onesu[8];
#pragma unroll
  for (int e = 0; e < 8; ++e) onesu[e] = 0x3f80;
  bf16x8 onesf = *(bf16x8*)onesu;

  // staging decomposition: lane -> (sub-row sr, swizzled 16B slot sc)
  const int sr = lane >> 3;                 // 0..7
  const int sc = (lane & 7) ^ sr;           // pre-swizzled source slot (involution)
  const u16* kstage = qkv + rowbase * 3072 + 1024 + nh * 64;       // + row*3072 + sc*8
  const u16* vstage = vtg + (size_t)bnh * 64 * 832;                // + d*832 + ktb + sc*8
  const int r0 = (wv << 4) + sr;            // this wave stages rows [wv*16, wv*16+16)
  u16* kd0 = &k_s[(wv << 4) * 64];
  u16* kd1 = &k_s[((wv << 4) + 8) * 64];
  u16* vd0 = &v_s[(wv << 4) * 64];
  u16* vd1 = &v_s[((wv << 4) + 8) * 64];
  const int swz = (fr & 7);                 // fragment-read swizzle key

  const float SSC = 0.125f * LOG2E;

  for (int kt = 0; kt < 13; ++kt){
    const int ktb = kt << 6;
    __syncthreads();                        // WAR: previous tile fully consumed
    {
      int jg0 = ktb + r0;       int jc0 = jg0 < 784 ? jg0 : 783;
      int jg1 = jg0 + 8;        int jc1 = jg1 < 784 ? jg1 : 783;
      gld16(kstage + (size_t)jc0 * 3072 + (sc << 3), kd0);
      gld16(kstage + (size_t)jc1 * 3072 + (sc << 3), kd1);
      gld16(vstage + (size_t)r0 * 832 + ktb + (sc << 3), vd0);
      gld16(vstage + (size_t)(r0 + 8) * 832 + ktb + (sc << 3), vd1);
    }
    __syncthreads();                        // staging visible (implicit vmcnt drain)

    // QK^T from swizzled LDS
    f32x4 S[2][4];
#pragma unroll
    for (int nf = 0; nf < 4; ++nf){
      int rb = (nf * 16 + fr) << 6;
      bf16x8 kf0 = *(const bf16x8*)&k_s[rb + ((fq ^ swz) << 3)];
      bf16x8 kf1 = *(const bf16x8*)&k_s[rb + (((fq + 4) ^ swz) << 3)];
#pragma unroll
      for (int mf = 0; mf < 2; ++mf){
        f32x4 s = z4;
        s = __builtin_amdgcn_mfma_f32_16x16x32_bf16(qf[mf][0], kf0, s, 0, 0, 0);
        s = __builtin_amdgcn_mfma_f32_16x16x32_bf16(qf[mf][1], kf1, s, 0, 0, 0);
        S[mf][nf] = s;
      }
    }

    int hj[4], wj[4]; bool val[4];
#pragma unroll
    for (int nf = 0; nf < 4; ++nf){
      int jg = ktb + nf * 16 + fr;
      int h = jg / 28;
      hj[nf] = h; wj[nf] = jg - h * 28; val[nf] = (jg < 784);
    }

    // p = exp2(SSC*S + bias2); bias via b64 reads of transposed tables
#pragma unroll
    for (int mf = 0; mf < 2; ++mf){
      int lrb = wq0 + mf * 16 + fq * 4;
#pragma unroll
      for (int nf = 0; nf < 4; ++nf){
        u16x4 h4 = *(const u16x4*)&gh_t[hj[nf] * GSTR + lrb];
        u16x4 w4 = *(const u16x4*)&gw_t[wj[nf] * GSTR + lrb];
#pragma unroll
        for (int r = 0; r < 4; ++r){
          float p = 0.f;
          if (val[nf])
            p = exp2f(fmaf(SSC, S[mf][nf][r], bf2f(h4[r]) + bf2f(w4[r])));
          p_s[(lrb + r) * PST + nf * 16 + fr] = f2bf(p);
        }
      }
    }

    // PV: P from wave-private LDS rows, V^T fragments from swizzled LDS
#pragma unroll
    for (int ks = 0; ks < 2; ++ks){
      bf16x8 pf0 = *(const bf16x8*)&p_s[(wq0 + fr) * PST + fq * 8 + ks * 32];
      bf16x8 pf1 = *(const bf16x8*)&p_s[(wq0 + 16 + fr) * PST + fq * 8 + ks * 32];
#pragma unroll
      for (int nf = 0; nf < 4; ++nf){
        bf16x8 vf = *(const bf16x8*)&v_s[((nf * 16 + fr) << 6) + (((fq + ks * 4) ^ swz) << 3)];
        acc[0][nf] = __builtin_amdgcn_mfma_f32_16x16x32_bf16(pf0, vf, acc[0][nf], 0, 0, 0);
        acc[1][nf] = __builtin_amdgcn_mfma_f32_16x16x32_bf16(pf1, vf, acc[1][nf], 0, 0, 0);
      }
      acc[0][4] = __builtin_amdgcn_mfma_f32_16x16x32_bf16(pf0, onesf, acc[0][4], 0, 0, 0);
      acc[1][4] = __builtin_amdgcn_mfma_f32_16x16x32_bf16(pf1, onesf, acc[1][4], 0, 0, 0);
    }
  }

#pragma unroll
  for (int mf = 0; mf < 2; ++mf)
#pragma unroll
    for (int r = 0; r < 4; ++r){
      int row = q0 + wq0 + mf * 16 + fq * 4 + r;
      if (row < 784){
        float inv = 1.f / acc[mf][4][r];   // ones-fragment: every column holds the row sum
        u16* dp = out + (rowbase + row) * 1024 + nh * 64 + fr;
#pragma unroll
        for (int nf = 0; nf < 4; ++nf)
          dp[nf * 16] = f2bf(acc[mf][nf][r] * inv);
      }
    }
}

// ---------------- im2col for 3x3 pad-1 conv: g[B,28,28,512](bf16) -> im[6272, 4608] ----------------
__global__ __launch_bounds__(256) void k_im2col(const u16* __restrict__ g, u16* __restrict__ im){
  int idx = blockIdx.x * 256 + threadIdx.x;
  int p  = idx / 576;
  int c8 = idx - p * 576;
  int k0 = c8 << 3;
  int t9 = k0 >> 9;
  int ci = k0 & 511;
  int ky = t9 / 3, kx = t9 - ky * 3;
  int bb = p / 784;
  int s = p - bb * 784;
  int h = s / 28, w = s - h * 28;
  int hh = h + ky - 1, ww = w + kx - 1;
  uint4 val = make_uint4(0u, 0u, 0u, 0u);
  if ((unsigned)hh < 28u && (unsigned)ww < 28u)
    val = *(const uint4*)&g[(((size_t)(bb * 28 + hh)) * 28 + ww) * 512 + ci];
  *(uint4*)&im[(size_t)p * 4608 + k0] = val;
}

// ---------------- orchestration ----------------
extern "C" void kernel_launch(void* const* d_in, const int* in_sizes, int n_in,
                              void* d_out, int out_size, void* d_ws, size_t ws_size,
                              hipStream_t stream)
{
  (void)in_sizes; (void)n_in; (void)out_size; (void)ws_size;
  const float* x      = (const float*)d_in[0];
  const float* n1w    = (const float*)d_in[1];
  const float* n1b    = (const float*)d_in[2];
  const float* qkv_w  = (const float*)d_in[3];
  const float* qkv_b  = (const float*)d_in[4];
  const float* proj_w = (const float*)d_in[5];
  const float* proj_b = (const float*)d_in[6];
  const float* rel_h  = (const float*)d_in[7];
  const float* rel_w  = (const float*)d_in[8];
  const float* n2w    = (const float*)d_in[9];
  const float* n2b    = (const float*)d_in[10];
  const float* fc1_w  = (const float*)d_in[11];
  const float* fc1_b  = (const float*)d_in[12];
  const float* fc2_w  = (const float*)d_in[13];
  const float* fc2_b  = (const float*)d_in[14];
  const float* c1w    = (const float*)d_in[15];
  const float* l1w    = (const float*)d_in[16];
  const float* l1b    = (const float*)d_in[17];
  const float* c2w    = (const float*)d_in[18];
  const float* l2w    = (const float*)d_in[19];
  const float* l2b    = (const float*)d_in[20];
  const float* c3w    = (const float*)d_in[21];
  const float* l3w    = (const float*)d_in[22];
  const float* l3b    = (const float*)d_in[23];

  char* ws = (char*)d_ws;
  size_t off = 0;
  auto alloc = [&](size_t bytes) -> void* {
    void* p = ws + off; off += (bytes + 255) & ~(size_t)255; return p;
  };
  const size_t M = 6272;
  u16* qkvT  = (u16*)alloc((size_t)3072 * 1024 * 2);
  u16* projT = (u16*)alloc((size_t)1024 * 1024 * 2);
  u16* fc1T  = (u16*)alloc((size_t)4096 * 1024 * 2);
  u16* fc2T  = (u16*)alloc((size_t)1024 * 4096 * 2);
  u16* c1T   = (u16*)alloc((size_t)512 * 1024 * 2);
  u16* c2T   = (u16*)alloc((size_t)512 * 4608 * 2);
  u16* c3T   = (u16*)alloc((size_t)1024 * 512 * 2);
  u16* qkvbuf = (u16*)alloc(M * 3072 * 2);
  u16* attn   = (u16*)alloc(M * 1024 * 2);
  u16* xn     = (u16*)alloc(M * 1024 * 2);
  float* x1   = (float*)alloc(M * 1024 * 4);
  u16* x2b    = (u16*)alloc(M * 1024 * 2);
  u16* c1buf  = (u16*)alloc(M * 512 * 2);
  u16* g1buf  = (u16*)alloc(M * 512 * 2);
  u16* hmlp   = qkvbuf;
  u16* im     = qkvbuf;
  u16* xn2    = xn;
  u16* c2buf  = c1buf;
  u16* g2buf  = g1buf;
  u16* c3buf  = attn;
  // vtg (13.6 MB) aliases x1 (25.7 MB): x1 is dead until the proj GEMM, which runs after attn.
  u16* vtg    = (u16*)x1;

  dim3 blk(256);
  k_transpose<<<dim3(3072/32, 1024/32), blk, 0, stream>>>(qkv_w, qkvT, 1024, 3072);
  k_transpose<<<dim3(1024/32, 1024/32), blk, 0, stream>>>(proj_w, projT, 1024, 1024);
  k_transpose<<<dim3(4096/32, 1024/32), blk, 0, stream>>>(fc1_w, fc1T, 1024, 4096);
  k_transpose<<<dim3(1024/32, 4096/32), blk, 0, stream>>>(fc2_w, fc2T, 4096, 1024);
  k_transpose<<<dim3(512/32, 1024/32),  blk, 0, stream>>>(c1w, c1T, 1024, 512);
  k_transpose<<<dim3(512/32, 4608/32),  blk, 0, stream>>>(c2w, c2T, 4608, 512);
  k_transpose<<<dim3(1024/32, 512/32),  blk, 0, stream>>>(c3w, c3T, 512, 1024);

  k_layernorm<true,false><<<6272, blk, 0, stream>>>(x, n1w, n1b, xn, 1024, 1e-5f);
  // qkv: high-TLP (1176 blocks) -> DEPTH=2
  k_gemm<2,true,false,false,true,false><<<dim3(24,49), blk, 0, stream>>>(
      xn, qkvT, qkv_b, nullptr, qkvbuf, nullptr, 3072, 1024);
  k_vtrans<<<dim3(128, 13), blk, 0, stream>>>(qkvbuf, vtg);
  k_attn7<<<896, blk, 0, stream>>>(qkvbuf, rel_h, rel_w, vtg, attn);
  // proj: low-TLP (392 blocks) -> DEPTH=3
  k_gemm<3,true,false,true,false,true><<<dim3(8,49), blk, 0, stream>>>(
      attn, projT, proj_b, x, nullptr, x1, 1024, 1024);
  k_layernorm<true,false><<<6272, blk, 0, stream>>>(x1, n2w, n2b, xn2, 1024, 1e-5f);
  // fc1: high-TLP (1568 blocks) -> DEPTH=2
  k_gemm<2,true,true,false,true,false><<<dim3(32,49), blk, 0, stream>>>(
      xn2, fc1T, fc1_b, nullptr, hmlp, nullptr, 4096, 1024);
  // fc2: low-TLP (392 blocks) -> DEPTH=3
  k_gemm<3,true,false,true,true,false><<<dim3(8,49), blk, 0, stream>>>(
      hmlp, fc2T, fc2_b, x1, x2b, nullptr, 1024, 4096);
  k_gemm<3,false,false,false,true,false><<<dim3(4,49), blk, 0, stream>>>(
      x2b, c1T, nullptr, nullptr, c1buf, nullptr, 512, 1024);
  k_layernorm<false,true><<<6272, blk, 0, stream>>>(c1buf, l1w, l1b, g1buf, 512, 1e-6f);
  k_im2col<<<14112, blk, 0, stream>>>(g1buf, im);
  k_gemm<3,false,false,false,true,false><<<dim3(4,49), blk, 0, stream>>>(
      im, c2T, nullptr, nullptr, c2buf, nullptr, 512, 4608);
  k_layernorm<false,true><<<6272, blk, 0, stream>>>(c2buf, l2w, l2b, g2buf, 512, 1e-6f);
  k_gemm<3,false,false,false,true,false><<<dim3(8,49), blk, 0, stream>>>(
      g2buf, c3T, nullptr, nullptr, c3buf, nullptr, 1024, 512);
  k_final<<<6272, blk, 0, stream>>>(c3buf, x2b, l3w, l3b, (float*)d_out);
}

// Round 9
// 678.803 us; speedup vs baseline: 1.0858x; 1.0741x over previous
//
#include <hip/hip_runtime.h>
#include <cstdint>
#include <cstddef>

using u16 = unsigned short;
using u32 = unsigned int;

// ---------------- helpers ----------------
__device__ __forceinline__ float bf2f(u16 u){
  union { u32 i; float f; } x; x.i = ((u32)u) << 16; return x.f;
}
__device__ __forceinline__ u16 f2bf(float f){
  union { float f; u32 i; } x; x.f = f;
  u32 r = x.i + 0x7fffu + ((x.i >> 16) & 1u);
  return (u16)(r >> 16);
}
__device__ __forceinline__ float gelu_f(float x){
  return 0.5f * x * (1.0f + erff(x * 0.70710678118654752f));
}
__device__ __forceinline__ void gld16(const void* g, void* l){
  // async global->LDS, 16B/lane; LDS dst = wave-uniform base + lane*16; global src per-lane
  __builtin_amdgcn_global_load_lds((__attribute__((address_space(1))) void*)(void*)g,
                                   (__attribute__((address_space(3))) void*)l, 16, 0, 0);
}

typedef __bf16 bf16x8 __attribute__((ext_vector_type(8)));
typedef float  f32x4  __attribute__((ext_vector_type(4)));
typedef u16    u16x4  __attribute__((ext_vector_type(4)));

// ---------------- weight transpose + cast: src fp32 [R,C] -> dst bf16 [C,R] ----------------
__global__ __launch_bounds__(256) void k_transpose(const float* __restrict__ src,
                                                   u16* __restrict__ dst, int R, int C){
  __shared__ u16 tile[32][33];
  int bx = blockIdx.x * 32;
  int by = blockIdx.y * 32;
  int tx = threadIdx.x & 31;
  int ty = threadIdx.x >> 5;
  for (int r = ty; r < 32; r += 8)
    tile[r][tx] = f2bf(src[(size_t)(by + r) * C + bx + tx]);
  __syncthreads();
  for (int r = ty; r < 32; r += 8)
    dst[(size_t)(bx + r) * R + by + tx] = tile[tx][r];
}

// ---------------- layernorm over last dim (cols = 1024 or 512), optional gelu, bf16 out ----------------
template<bool IN_F32, bool DO_GELU>
__global__ __launch_bounds__(256) void k_layernorm(const void* __restrict__ inp,
    const float* __restrict__ w, const float* __restrict__ bsh,
    u16* __restrict__ out, int cols, float eps){
  int row = blockIdx.x, t = threadIdx.x;
  size_t base = (size_t)row * cols;
  const float* inf = (const float*)inp;
  const u16*  inb = (const u16*)inp;
  float v[4];
  int ep = cols >> 8;
  float s = 0.f, ss = 0.f;
  for (int e = 0; e < ep; ++e){
    int idx = t + (e << 8);
    float x = IN_F32 ? inf[base + idx] : bf2f(inb[base + idx]);
    v[e] = x; s += x; ss += x * x;
  }
#pragma unroll
  for (int off = 1; off < 64; off <<= 1){
    s  += __shfl_xor(s, off, 64);
    ss += __shfl_xor(ss, off, 64);
  }
  __shared__ float red[8];
  int wv = t >> 6;
  if ((t & 63) == 0){ red[wv] = s; red[4 + wv] = ss; }
  __syncthreads();
  s  = red[0] + red[1] + red[2] + red[3];
  ss = red[4] + red[5] + red[6] + red[7];
  float inv = 1.f / (float)cols;
  float mean = s * inv;
  float var = ss * inv - mean * mean;
  float rs = rsqrtf(var + eps);
  for (int e = 0; e < ep; ++e){
    int idx = t + (e << 8);
    float y = (v[e] - mean) * rs * w[idx] + bsh[idx];
    if (DO_GELU) y = gelu_f(y);
    out[base + idx] = f2bf(y);
  }
}

// ---------------- final: out(fp32) = x2(bf16) + LN(c3; ln3) , cols=1024 ----------------
__global__ __launch_bounds__(256) void k_final(const u16* __restrict__ c3,
    const u16* __restrict__ x2, const float* __restrict__ w,
    const float* __restrict__ bsh, float* __restrict__ out){
  int row = blockIdx.x, t = threadIdx.x;
  size_t base = (size_t)row << 10;
  float v[4];
  float s = 0.f, ss = 0.f;
#pragma unroll
  for (int e = 0; e < 4; ++e){
    int idx = t + (e << 8);
    float x = bf2f(c3[base + idx]);
    v[e] = x; s += x; ss += x * x;
  }
#pragma unroll
  for (int off = 1; off < 64; off <<= 1){
    s  += __shfl_xor(s, off, 64);
    ss += __shfl_xor(ss, off, 64);
  }
  __shared__ float red[8];
  int wv = t >> 6;
  if ((t & 63) == 0){ red[wv] = s; red[4 + wv] = ss; }
  __syncthreads();
  s  = red[0] + red[1] + red[2] + red[3];
  ss = red[4] + red[5] + red[6] + red[7];
  float mean = s * (1.f/1024.f);
  float var = ss * (1.f/1024.f) - mean * mean;
  float rs = rsqrtf(var + 1e-6f);
#pragma unroll
  for (int e = 0; e < 4; ++e){
    int idx = t + (e << 8);
    float y = (v[e] - mean) * rs * w[idx] + bsh[idx];
    out[base + idx] = bf2f(x2[base + idx]) + y;
  }
}

// ---------------- MFMA GEMM: C[M,N] = A[M,K](bf16) * Bt[N,K]^T(bf16) (+fp32 bias/res, gelu) ----------------
// 128x128 tile, BK=32, 4 waves, DEPTH=2 LDS pipeline, counted vmcnt (never 0 in loop).
// CONV: A-staging computes 3x3-pad1 im2col addressing on the fly (tap is wave-uniform
// per K-iter since 32-col chunks never straddle a 512-col tap); OOB rows read a zero buffer.
// OUTB epilogue: C tile staged to LDS (reusing As/Bs, 32KB) then stored with 256B-coalesced
// uint4 writes. Math identical to the direct path; only the store pattern changes.
// XCD-aware bijective block swizzle (T1/m204).
template<int DEPTH, bool BIAS, bool GELU, bool RES, bool OUTB, bool OUTF, bool CONV>
__global__ __launch_bounds__(256, 2) void k_gemm(
    const u16* __restrict__ A, const u16* __restrict__ Bt,
    const float* __restrict__ bias, const float* __restrict__ resf,
    u16* __restrict__ outb, float* __restrict__ outf,
    const u16* __restrict__ zb, int N, int K)
{
  __shared__ __align__(16) u16 smem[DEPTH * 2 * 128 * 32];   // DEPTH=2: 32KB; also C-tile (16384 u16)
  u16* Asb = smem;                     // As[buf] = Asb + buf*4096
  u16* Bsb = smem + DEPTH * 4096;      // Bs[buf] = Bsb + buf*4096
  int t = threadIdx.x, lane = t & 63, wv = t >> 6;

  int nbx = gridDim.x;
  int nwg = nbx * gridDim.y;
  int li  = blockIdx.y * nbx + blockIdx.x;
  int qc = nwg >> 3, rc = nwg & 7;
  int xcd = li & 7, jj = li >> 3;
  int wg = (xcd < rc ? xcd * (qc + 1) : rc * (qc + 1) + (xcd - rc) * qc) + jj;
  int byy = wg / nbx;
  int bxx = wg - byy * nbx;
  int m0 = byy << 7, n0 = bxx << 7;

  int wm = (wv >> 1) << 6, wn = (wv & 1) << 6;

  f32x4 acc[4][4];
  const f32x4 z4 = {0.f, 0.f, 0.f, 0.f};
#pragma unroll
  for (int i = 0; i < 4; ++i)
#pragma unroll
    for (int j = 0; j < 4; ++j) acc[i][j] = z4;

  int srow = (wv << 5) + (lane >> 2);
  int skp  = (lane & 3) << 3;
  const u16* Ag = A  + (size_t)(m0 + srow) * K + skp;
  const u16* Bg = Bt + (size_t)(n0 + srow) * K + skp;
  const size_t rowskip = (size_t)16 * K;

  // CONV per-lane im2col decode for staged rows p0=m0+srow and p1=p0+16
  int bb0 = 0, h0 = 0, w0 = 0, bb1 = 0, h1 = 0, w1 = 0;
  if (CONV){
    int p0 = m0 + srow;
    bb0 = p0 / 784; int s0i = p0 - bb0 * 784; h0 = s0i / 28; w0 = s0i - h0 * 28;
    int p1 = p0 + 16;
    bb1 = p1 / 784; int s1i = p1 - bb1 * 784; h1 = s1i / 28; w1 = s1i - h1 * 28;
  }

  int fr = lane & 15, fq = (lane >> 4) << 3;

  auto stage = [&](int buf, int k0){
    u16* a0 = Asb + buf * 4096 + (wv << 5) * 32;
    u16* b0 = Bsb + buf * 4096 + (wv << 5) * 32;
    if (CONV){
      int tap = k0 >> 9;                       // 0..8, wave-uniform
      int ky = tap / 3, kx = tap - ky * 3;
      int ci = (k0 & 511) + skp;
      int hh0 = h0 + ky - 1, ww0 = w0 + kx - 1;
      int hh1 = h1 + ky - 1, ww1 = w1 + kx - 1;
      const u16* s0 = ((unsigned)hh0 < 28u && (unsigned)ww0 < 28u)
          ? A + (((size_t)(bb0 * 28 + hh0)) * 28 + ww0) * 512 + ci : zb;
      const u16* s1 = ((unsigned)hh1 < 28u && (unsigned)ww1 < 28u)
          ? A + (((size_t)(bb1 * 28 + hh1)) * 28 + ww1) * 512 + ci : zb;
      gld16(s0, a0);
      gld16(s1, a0 + 16 * 32);
    } else {
      gld16(Ag + k0, a0);
      gld16(Ag + rowskip + k0, a0 + 16 * 32);
    }
    gld16(Bg + k0, b0);
    gld16(Bg + rowskip + k0, b0 + 16 * 32);
  };

  auto compute = [&](int buf){
    const u16* As = Asb + buf * 4096;
    const u16* Bs = Bsb + buf * 4096;
    bf16x8 af[4], bfr[4];
#pragma unroll
    for (int i = 0; i < 4; ++i)
      af[i] = *(const bf16x8*)&As[(wm + i * 16 + fr) * 32 + fq];
#pragma unroll
    for (int j = 0; j < 4; ++j)
      bfr[j] = *(const bf16x8*)&Bs[(wn + j * 16 + fr) * 32 + fq];
#pragma unroll
    for (int i = 0; i < 4; ++i)
#pragma unroll
      for (int j = 0; j < 4; ++j)
        acc[i][j] = __builtin_amdgcn_mfma_f32_16x16x32_bf16(af[i], bfr[j], acc[i][j], 0, 0, 0);
  };

  int nk = K >> 5;
  stage(0, 0);                       // prologue: one tile in flight

  for (int kk = 0; kk < nk; ++kk){
    int nxt = kk + 1;
    if (nxt < nk){
      stage(nxt & 1, nxt << 5);
      asm volatile("s_waitcnt vmcnt(4)" ::: "memory");   // tile kk landed; next stays in flight
    } else {
      asm volatile("s_waitcnt vmcnt(0)" ::: "memory");
    }
    __builtin_amdgcn_s_barrier();                        // all waves' tile-kk stores visible
    compute(kk & 1);
    // ds_reads drained via MFMA data-deps before this barrier; buffer kk&1 is only
    // re-staged (as tile kk+2) after all waves pass it.
    __builtin_amdgcn_s_barrier();
  }

  int rr = (lane >> 4) << 2;
  int cc = lane & 15;
  if (OUTB){
    // pass 1: full epilogue math (unchanged), staged to LDS C-tile (reuses As/Bs)
    u16* Cs = smem;
#pragma unroll
    for (int i = 0; i < 4; ++i)
#pragma unroll
      for (int j = 0; j < 4; ++j){
        int lc = wn + j * 16 + cc;
        int gc = n0 + lc;
        float bb = BIAS ? bias[gc] : 0.f;
#pragma unroll
        for (int r = 0; r < 4; ++r){
          int lr = wm + i * 16 + rr + r;
          float vv = acc[i][j][r] + bb;
          if (RES) vv += resf[(size_t)(m0 + lr) * N + gc];
          if (GELU) vv = gelu_f(vv);
          Cs[lr * 128 + lc] = f2bf(vv);
        }
      }
    __syncthreads();
    // pass 2: linear 256B-coalesced stores (16B per lane, consecutive within a row)
#pragma unroll
    for (int it = 0; it < 8; ++it){
      int flat = it * 256 + t;            // 2048 chunks of 8 u16
      int row = flat >> 4;
      int col = (flat & 15) << 3;
      *(uint4*)&outb[(size_t)(m0 + row) * N + n0 + col] = *(const uint4*)&Cs[row * 128 + col];
    }
  } else {
    // OUTF (fp32) path: direct stores (proj only)
#pragma unroll
    for (int i = 0; i < 4; ++i)
#pragma unroll
      for (int j = 0; j < 4; ++j){
        int gc = n0 + wn + j * 16 + cc;
        float bb = BIAS ? bias[gc] : 0.f;
#pragma unroll
        for (int r = 0; r < 4; ++r){
          int gr = m0 + wm + i * 16 + rr + r;
          size_t idx = (size_t)gr * N + gc;
          float vv = acc[i][j][r] + bb;
          if (RES) vv += resf[idx];
          if (GELU) vv = gelu_f(vv);
          outf[idx] = vv;
        }
      }
  }
}

// ---------------- V pre-transpose: qkvbuf V slice -> vtg[bnh][64 d][832 j] (bf16, j zero-padded) ----------------
__global__ __launch_bounds__(256) void k_vtrans(const u16* __restrict__ qkv, u16* __restrict__ vtg){
  __shared__ u32 tile[64][33];
  int bnh = blockIdx.x;            // 0..127
  int st  = blockIdx.y;            // 0..12
  int b = bnh >> 4, nh = bnh & 15;
  int t = threadIdx.x;
  int tx = t & 31;                 // dword column (2 u16)
  int ty = t >> 5;                 // 0..7
  const u16* src = qkv + (size_t)b * 784 * 3072 + 2048 + nh * 64;
  int s0 = st << 6;
  for (int r = ty; r < 64; r += 8){
    int s = s0 + r;
    u32 val = 0u;
    if (s < 784) val = *(const u32*)(src + (size_t)s * 3072 + tx * 2);
    tile[r][tx] = val;
  }
  __syncthreads();
  u16* dst = vtg + (size_t)bnh * 64 * 832 + s0;
  for (int d = ty; d < 64; d += 8){
    u32 lo = tile[2 * tx][d >> 1];
    u32 hi = tile[2 * tx + 1][d >> 1];
    u16 a  = (d & 1) ? (u16)(lo >> 16) : (u16)lo;
    u16 bb = (d & 1) ? (u16)(hi >> 16) : (u16)hi;
    u32 pk = (u32)a | ((u32)bb << 16);
    *(u32*)(dst + (size_t)d * 832 + 2 * tx) = pk;
  }
}

// ---------------- MFMA flash attention v7: coalesced LDS staging + XOR swizzle ----------------
#define PST 72
#define GSTR 132
#define LOG2E 1.4426950408889634f
__global__ __launch_bounds__(256, 3) void k_attn7(const u16* __restrict__ qkv,
    const float* __restrict__ relh, const float* __restrict__ relw,
    const u16* __restrict__ vtg, u16* __restrict__ out)
{
  __shared__ __align__(16) u16 k_s[64 * 64];        // 8 KB, swizzled K tile (row j, col d)
  __shared__ __align__(16) u16 v_s[64 * 64];        // 8 KB, swizzled V^T tile (row d, col j)
  __shared__ __align__(16) u16 p_s[128 * PST];      // 18.4 KB, P; also Rh/Rw staging
  __shared__ __align__(16) u16 gh_t[28 * GSTR];     // 7.4 KB, transposed bias (x log2e)
  __shared__ __align__(16) u16 gw_t[28 * GSTR];     // 7.4 KB

  const int t = threadIdx.x, lane = t & 63, wv = t >> 6;
  int id = blockIdx.x;
  int xr = id & 7, rest = id >> 3;
  int qt = rest % 7, gg = rest / 7;
  int bnh = xr + (gg << 3);
  const int b = bnh >> 4, nh = bnh & 15;
  const int q0 = qt << 7;
  const size_t rowbase = (size_t)b * 784;
  const int wq0 = wv << 5;
  const int fr = lane & 15;
  const int fq = lane >> 4;

  // stage Rh/Rw (bf16) into p_s region
  u16* rh_s = p_s;
  u16* rw_s = p_s + 64 * PST;
  {
    int row = t >> 2, c0 = (t & 3) << 4;
    u16 bh_[16], bw_[16];
    if (row < 55){
      const float* ph = relh + row * 64 + c0;
      const float* pw = relw + row * 64 + c0;
#pragma unroll
      for (int e = 0; e < 16; ++e){ bh_[e] = f2bf(ph[e]); bw_[e] = f2bf(pw[e]); }
    } else {
#pragma unroll
      for (int e = 0; e < 16; ++e){ bh_[e] = 0; bw_[e] = 0; }
    }
    *(uint4*)&rh_s[row * PST + c0]     = *(uint4*)bh_;
    *(uint4*)&rh_s[row * PST + c0 + 8] = *(uint4*)(bh_ + 8);
    *(uint4*)&rw_s[row * PST + c0]     = *(uint4*)bw_;
    *(uint4*)&rw_s[row * PST + c0 + 8] = *(uint4*)(bw_ + 8);
  }

  // Q fragments (registers)
  bf16x8 qf[2][2];
#pragma unroll
  for (int mf = 0; mf < 2; ++mf)
#pragma unroll
    for (int ks = 0; ks < 2; ++ks){
      int row = q0 + wq0 + mf * 16 + fr;
      if (row < 784){
        qf[mf][ks] = *(const bf16x8*)(qkv + (rowbase + row) * 3072 + nh * 64 + fq * 8 + ks * 32);
      } else {
        uint4 z = {0u,0u,0u,0u}; qf[mf][ks] = *(bf16x8*)&z;
      }
    }
  __syncthreads();

  const f32x4 z4 = {0.f,0.f,0.f,0.f};
  // ---- decomposed rel-pos bias via MFMA -> transposed tables gt[kk][lr], pre-scaled by log2e ----
#pragma unroll
  for (int which = 0; which < 2; ++which){
    const u16* rs = which ? rw_s : rh_s;
    f32x4 G[2][4];
#pragma unroll
    for (int mf = 0; mf < 2; ++mf)
#pragma unroll
      for (int nf = 0; nf < 4; ++nf) G[mf][nf] = z4;
#pragma unroll
    for (int nf = 0; nf < 4; ++nf){
      bf16x8 rf0 = *(const bf16x8*)&rs[(nf * 16 + fr) * PST + fq * 8];
      bf16x8 rf1 = *(const bf16x8*)&rs[(nf * 16 + fr) * PST + fq * 8 + 32];
#pragma unroll
      for (int mf = 0; mf < 2; ++mf){
        G[mf][nf] = __builtin_amdgcn_mfma_f32_16x16x32_bf16(qf[mf][0], rf0, G[mf][nf], 0, 0, 0);
        G[mf][nf] = __builtin_amdgcn_mfma_f32_16x16x32_bf16(qf[mf][1], rf1, G[mf][nf], 0, 0, 0);
      }
    }
    u16* gt = which ? gw_t : gh_t;
#pragma unroll
    for (int mf = 0; mf < 2; ++mf)
#pragma unroll
      for (int r = 0; r < 4; ++r){
        int lr = wq0 + mf * 16 + fq * 4 + r;
        int grow = q0 + lr;
        int hq = grow / 28;
        int coord = which ? (grow - hq * 28) : hq;
#pragma unroll
        for (int nf = 0; nf < 4; ++nf){
          int j = nf * 16 + fr;
          int kk = coord + 27 - j;
          if ((unsigned)kk < 28u) gt[kk * GSTR + lr] = f2bf(G[mf][nf][r] * LOG2E);
        }
      }
  }
  __syncthreads();   // tables + Rh/Rw reads complete before p_s reuse / k_s staging

  f32x4 acc[2][5];
#pragma unroll
  for (int mf = 0; mf < 2; ++mf)
#pragma unroll
    for (int nf = 0; nf < 5; ++nf) acc[mf][nf] = z4;

  u16 onesu[8];
#pragma unroll
  for (int e = 0; e < 8; ++e) onesu[e] = 0x3f80;
  bf16x8 onesf = *(bf16x8*)onesu;

  // staging decomposition: lane -> (sub-row sr, swizzled 16B slot sc)
  const int sr = lane >> 3;                 // 0..7
  const int sc = (lane & 7) ^ sr;           // pre-swizzled source slot (involution)
  const u16* kstage = qkv + rowbase * 3072 + 1024 + nh * 64;       // + row*3072 + sc*8
  const u16* vstage = vtg + (size_t)bnh * 64 * 832;                // + d*832 + ktb + sc*8
  const int r0 = (wv << 4) + sr;            // this wave stages rows [wv*16, wv*16+16)
  u16* kd0 = &k_s[(wv << 4) * 64];
  u16* kd1 = &k_s[((wv << 4) + 8) * 64];
  u16* vd0 = &v_s[(wv << 4) * 64];
  u16* vd1 = &v_s[((wv << 4) + 8) * 64];
  const int swz = (fr & 7);                 // fragment-read swizzle key

  const float SSC = 0.125f * LOG2E;

  for (int kt = 0; kt < 13; ++kt){
    const int ktb = kt << 6;
    __syncthreads();                        // WAR: previous tile fully consumed
    {
      int jg0 = ktb + r0;       int jc0 = jg0 < 784 ? jg0 : 783;
      int jg1 = jg0 + 8;        int jc1 = jg1 < 784 ? jg1 : 783;
      gld16(kstage + (size_t)jc0 * 3072 + (sc << 3), kd0);
      gld16(kstage + (size_t)jc1 * 3072 + (sc << 3), kd1);
      gld16(vstage + (size_t)r0 * 832 + ktb + (sc << 3), vd0);
      gld16(vstage + (size_t)(r0 + 8) * 832 + ktb + (sc << 3), vd1);
    }
    __syncthreads();                        // staging visible (implicit vmcnt drain)

    // QK^T from swizzled LDS
    f32x4 S[2][4];
#pragma unroll
    for (int nf = 0; nf < 4; ++nf){
      int rb = (nf * 16 + fr) << 6;
      bf16x8 kf0 = *(const bf16x8*)&k_s[rb + ((fq ^ swz) << 3)];
      bf16x8 kf1 = *(const bf16x8*)&k_s[rb + (((fq + 4) ^ swz) << 3)];
#pragma unroll
      for (int mf = 0; mf < 2; ++mf){
        f32x4 s = z4;
        s = __builtin_amdgcn_mfma_f32_16x16x32_bf16(qf[mf][0], kf0, s, 0, 0, 0);
        s = __builtin_amdgcn_mfma_f32_16x16x32_bf16(qf[mf][1], kf1, s, 0, 0, 0);
        S[mf][nf] = s;
      }
    }

    int hj[4], wj[4]; bool val[4];
#pragma unroll
    for (int nf = 0; nf < 4; ++nf){
      int jg = ktb + nf * 16 + fr;
      int h = jg / 28;
      hj[nf] = h; wj[nf] = jg - h * 28; val[nf] = (jg < 784);
    }

    // p = exp2(SSC*S + bias2); bias via b64 reads of transposed tables
#pragma unroll
    for (int mf = 0; mf < 2; ++mf){
      int lrb = wq0 + mf * 16 + fq * 4;
#pragma unroll
      for (int nf = 0; nf < 4; ++nf){
        u16x4 h4 = *(const u16x4*)&gh_t[hj[nf] * GSTR + lrb];
        u16x4 w4 = *(const u16x4*)&gw_t[wj[nf] * GSTR + lrb];
#pragma unroll
        for (int r = 0; r < 4; ++r){
          float p = 0.f;
          if (val[nf])
            p = exp2f(fmaf(SSC, S[mf][nf][r], bf2f(h4[r]) + bf2f(w4[r])));
          p_s[(lrb + r) * PST + nf * 16 + fr] = f2bf(p);
        }
      }
    }

    // PV: P from wave-private LDS rows, V^T fragments from swizzled LDS
#pragma unroll
    for (int ks = 0; ks < 2; ++ks){
      bf16x8 pf0 = *(const bf16x8*)&p_s[(wq0 + fr) * PST + fq * 8 + ks * 32];
      bf16x8 pf1 = *(const bf16x8*)&p_s[(wq0 + 16 + fr) * PST + fq * 8 + ks * 32];
#pragma unroll
      for (int nf = 0; nf < 4; ++nf){
        bf16x8 vf = *(const bf16x8*)&v_s[((nf * 16 + fr) << 6) + (((fq + ks * 4) ^ swz) << 3)];
        acc[0][nf] = __builtin_amdgcn_mfma_f32_16x16x32_bf16(pf0, vf, acc[0][nf], 0, 0, 0);
        acc[1][nf] = __builtin_amdgcn_mfma_f32_16x16x32_bf16(pf1, vf, acc[1][nf], 0, 0, 0);
      }
      acc[0][4] = __builtin_amdgcn_mfma_f32_16x16x32_bf16(pf0, onesf, acc[0][4], 0, 0, 0);
      acc[1][4] = __builtin_amdgcn_mfma_f32_16x16x32_bf16(pf1, onesf, acc[1][4], 0, 0, 0);
    }
  }

#pragma unroll
  for (int mf = 0; mf < 2; ++mf)
#pragma unroll
    for (int r = 0; r < 4; ++r){
      int row = q0 + wq0 + mf * 16 + fq * 4 + r;
      if (row < 784){
        float inv = 1.f / acc[mf][4][r];   // ones-fragment: every column holds the row sum
        u16* dp = out + (rowbase + row) * 1024 + nh * 64 + fr;
#pragma unroll
        for (int nf = 0; nf < 4; ++nf)
          dp[nf * 16] = f2bf(acc[mf][nf][r] * inv);
      }
    }
}

// ---------------- orchestration ----------------
extern "C" void kernel_launch(void* const* d_in, const int* in_sizes, int n_in,
                              void* d_out, int out_size, void* d_ws, size_t ws_size,
                              hipStream_t stream)
{
  (void)in_sizes; (void)n_in; (void)out_size; (void)ws_size;
  const float* x      = (const float*)d_in[0];
  const float* n1w    = (const float*)d_in[1];
  const float* n1b    = (const float*)d_in[2];
  const float* qkv_w  = (const float*)d_in[3];
  const float* qkv_b  = (const float*)d_in[4];
  const float* proj_w = (const float*)d_in[5];
  const float* proj_b = (const float*)d_in[6];
  const float* rel_h  = (const float*)d_in[7];
  const float* rel_w  = (const float*)d_in[8];
  const float* n2w    = (const float*)d_in[9];
  const float* n2b    = (const float*)d_in[10];
  const float* fc1_w  = (const float*)d_in[11];
  const float* fc1_b  = (const float*)d_in[12];
  const float* fc2_w  = (const float*)d_in[13];
  const float* fc2_b  = (const float*)d_in[14];
  const float* c1w    = (const float*)d_in[15];
  const float* l1w    = (const float*)d_in[16];
  const float* l1b    = (const float*)d_in[17];
  const float* c2w    = (const float*)d_in[18];
  const float* l2w    = (const float*)d_in[19];
  const float* l2b    = (const float*)d_in[20];
  const float* c3w    = (const float*)d_in[21];
  const float* l3w    = (const float*)d_in[22];
  const float* l3b    = (const float*)d_in[23];

  char* ws = (char*)d_ws;
  size_t off = 0;
  auto alloc = [&](size_t bytes) -> void* {
    void* p = ws + off; off += (bytes + 255) & ~(size_t)255; return p;
  };
  const size_t M = 6272;
  u16* qkvT  = (u16*)alloc((size_t)3072 * 1024 * 2);
  u16* projT = (u16*)alloc((size_t)1024 * 1024 * 2);
  u16* fc1T  = (u16*)alloc((size_t)4096 * 1024 * 2);
  u16* fc2T  = (u16*)alloc((size_t)1024 * 4096 * 2);
  u16* c1T   = (u16*)alloc((size_t)512 * 1024 * 2);
  u16* c2T   = (u16*)alloc((size_t)512 * 4608 * 2);
  u16* c3T   = (u16*)alloc((size_t)1024 * 512 * 2);
  u16* qkvbuf = (u16*)alloc(M * 3072 * 2);
  u16* attn   = (u16*)alloc(M * 1024 * 2);
  u16* xn     = (u16*)alloc(M * 1024 * 2);
  float* x1   = (float*)alloc(M * 1024 * 4);
  u16* x2b    = (u16*)alloc(M * 1024 * 2);
  u16* c1buf  = (u16*)alloc(M * 512 * 2);
  u16* g1buf  = (u16*)alloc(M * 512 * 2);
  u16* zbuf   = (u16*)alloc(256);
  u16* hmlp   = qkvbuf;
  u16* xn2    = xn;
  u16* c2buf  = c1buf;
  u16* g2buf  = g1buf;
  u16* c3buf  = attn;
  // vtg (13.6 MB) aliases x1 (25.7 MB): x1 is dead until the proj GEMM, which runs after attn.
  u16* vtg    = (u16*)x1;

  hipMemsetAsync(zbuf, 0, 256, stream);   // zero source for conv-padding staging

  dim3 blk(256);
  k_transpose<<<dim3(3072/32, 1024/32), blk, 0, stream>>>(qkv_w, qkvT, 1024, 3072);
  k_transpose<<<dim3(1024/32, 1024/32), blk, 0, stream>>>(proj_w, projT, 1024, 1024);
  k_transpose<<<dim3(4096/32, 1024/32), blk, 0, stream>>>(fc1_w, fc1T, 1024, 4096);
  k_transpose<<<dim3(1024/32, 4096/32), blk, 0, stream>>>(fc2_w, fc2T, 4096, 1024);
  k_transpose<<<dim3(512/32, 1024/32),  blk, 0, stream>>>(c1w, c1T, 1024, 512);
  k_transpose<<<dim3(512/32, 4608/32),  blk, 0, stream>>>(c2w, c2T, 4608, 512);
  k_transpose<<<dim3(1024/32, 512/32),  blk, 0, stream>>>(c3w, c3T, 512, 1024);

  k_layernorm<true,false><<<6272, blk, 0, stream>>>(x, n1w, n1b, xn, 1024, 1e-5f);
  k_gemm<2,true,false,false,true,false,false><<<dim3(24,49), blk, 0, stream>>>(
      xn, qkvT, qkv_b, nullptr, qkvbuf, nullptr, nullptr, 3072, 1024);
  k_vtrans<<<dim3(128, 13), blk, 0, stream>>>(qkvbuf, vtg);
  k_attn7<<<896, blk, 0, stream>>>(qkvbuf, rel_h, rel_w, vtg, attn);
  k_gemm<2,true,false,true,false,true,false><<<dim3(8,49), blk, 0, stream>>>(
      attn, projT, proj_b, x, nullptr, x1, nullptr, 1024, 1024);
  k_layernorm<true,false><<<6272, blk, 0, stream>>>(x1, n2w, n2b, xn2, 1024, 1e-5f);
  k_gemm<2,true,true,false,true,false,false><<<dim3(32,49), blk, 0, stream>>>(
      xn2, fc1T, fc1_b, nullptr, hmlp, nullptr, nullptr, 4096, 1024);
  k_gemm<2,true,false,true,true,false,false><<<dim3(8,49), blk, 0, stream>>>(
      hmlp, fc2T, fc2_b, x1, x2b, nullptr, nullptr, 1024, 4096);
  k_gemm<2,false,false,false,true,false,false><<<dim3(4,49), blk, 0, stream>>>(
      x2b, c1T, nullptr, nullptr, c1buf, nullptr, nullptr, 512, 1024);
  k_layernorm<false,true><<<6272, blk, 0, stream>>>(c1buf, l1w, l1b, g1buf, 512, 1e-6f);
  // c2: fused im2col conv GEMM (A = g1buf, 3x3 pad-1 addressing in staging)
  k_gemm<2,false,false,false,true,false,true><<<dim3(4,49), blk, 0, stream>>>(
      g1buf, c2T, nullptr, nullptr, c2buf, nullptr, zbuf, 512, 4608);
  k_layernorm<false,true><<<6272, blk, 0, stream>>>(c2buf, l2w, l2b, g2buf, 512, 1e-6f);
  k_gemm<2,false,false,false,true,false,false><<<dim3(8,49), blk, 0, stream>>>(
      g2buf, c3T, nullptr, nullptr, c3buf, nullptr, nullptr, 1024, 512);
  k_final<<<6272, blk, 0, stream>>>(c3buf, x2b, l3w, l3b, (float*)d_out);
}

// Round 10
// 665.704 us; speedup vs baseline: 1.1072x; 1.0197x over previous
//
#include <hip/hip_runtime.h>
#include <cstdint>
#include <cstddef>

using u16 = unsigned short;
using u32 = unsigned int;

// ---------------- helpers ----------------
__device__ __forceinline__ float bf2f(u16 u){
  union { u32 i; float f; } x; x.i = ((u32)u) << 16; return x.f;
}
__device__ __forceinline__ u16 f2bf(float f){
  union { float f; u32 i; } x; x.f = f;
  u32 r = x.i + 0x7fffu + ((x.i >> 16) & 1u);
  return (u16)(r >> 16);
}
__device__ __forceinline__ float gelu_f(float x){
  return 0.5f * x * (1.0f + erff(x * 0.70710678118654752f));
}
__device__ __forceinline__ void gld16(const void* g, void* l){
  // async global->LDS, 16B/lane; LDS dst = wave-uniform base + lane*16; global src per-lane
  __builtin_amdgcn_global_load_lds((__attribute__((address_space(1))) void*)(void*)g,
                                   (__attribute__((address_space(3))) void*)l, 16, 0, 0);
}

typedef __bf16 bf16x8 __attribute__((ext_vector_type(8)));
typedef float  f32x4  __attribute__((ext_vector_type(4)));
typedef u16    u16x4  __attribute__((ext_vector_type(4)));

// ---------------- weight transpose + cast: src fp32 [R,C] -> dst bf16 [C,R] ----------------
__global__ __launch_bounds__(256) void k_transpose(const float* __restrict__ src,
                                                   u16* __restrict__ dst, int R, int C){
  __shared__ u16 tile[32][33];
  int bx = blockIdx.x * 32;
  int by = blockIdx.y * 32;
  int tx = threadIdx.x & 31;
  int ty = threadIdx.x >> 5;
  for (int r = ty; r < 32; r += 8)
    tile[r][tx] = f2bf(src[(size_t)(by + r) * C + bx + tx]);
  __syncthreads();
  for (int r = ty; r < 32; r += 8)
    dst[(size_t)(bx + r) * R + by + tx] = tile[tx][r];
}

// ---------------- layernorm over last dim (cols = 1024 or 512), optional gelu, bf16 out ----------------
template<bool IN_F32, bool DO_GELU>
__global__ __launch_bounds__(256) void k_layernorm(const void* __restrict__ inp,
    const float* __restrict__ w, const float* __restrict__ bsh,
    u16* __restrict__ out, int cols, float eps){
  int row = blockIdx.x, t = threadIdx.x;
  size_t base = (size_t)row * cols;
  const float* inf = (const float*)inp;
  const u16*  inb = (const u16*)inp;
  float v[4];
  int ep = cols >> 8;
  float s = 0.f, ss = 0.f;
  for (int e = 0; e < ep; ++e){
    int idx = t + (e << 8);
    float x = IN_F32 ? inf[base + idx] : bf2f(inb[base + idx]);
    v[e] = x; s += x; ss += x * x;
  }
#pragma unroll
  for (int off = 1; off < 64; off <<= 1){
    s  += __shfl_xor(s, off, 64);
    ss += __shfl_xor(ss, off, 64);
  }
  __shared__ float red[8];
  int wv = t >> 6;
  if ((t & 63) == 0){ red[wv] = s; red[4 + wv] = ss; }
  __syncthreads();
  s  = red[0] + red[1] + red[2] + red[3];
  ss = red[4] + red[5] + red[6] + red[7];
  float inv = 1.f / (float)cols;
  float mean = s * inv;
  float var = ss * inv - mean * mean;
  float rs = rsqrtf(var + eps);
  for (int e = 0; e < ep; ++e){
    int idx = t + (e << 8);
    float y = (v[e] - mean) * rs * w[idx] + bsh[idx];
    if (DO_GELU) y = gelu_f(y);
    out[base + idx] = f2bf(y);
  }
}

// ---------------- final: out(fp32) = x2(bf16) + LN(c3; ln3) , cols=1024 ----------------
__global__ __launch_bounds__(256) void k_final(const u16* __restrict__ c3,
    const u16* __restrict__ x2, const float* __restrict__ w,
    const float* __restrict__ bsh, float* __restrict__ out){
  int row = blockIdx.x, t = threadIdx.x;
  size_t base = (size_t)row << 10;
  float v[4];
  float s = 0.f, ss = 0.f;
#pragma unroll
  for (int e = 0; e < 4; ++e){
    int idx = t + (e << 8);
    float x = bf2f(c3[base + idx]);
    v[e] = x; s += x; ss += x * x;
  }
#pragma unroll
  for (int off = 1; off < 64; off <<= 1){
    s  += __shfl_xor(s, off, 64);
    ss += __shfl_xor(ss, off, 64);
  }
  __shared__ float red[8];
  int wv = t >> 6;
  if ((t & 63) == 0){ red[wv] = s; red[4 + wv] = ss; }
  __syncthreads();
  s  = red[0] + red[1] + red[2] + red[3];
  ss = red[4] + red[5] + red[6] + red[7];
  float mean = s * (1.f/1024.f);
  float var = ss * (1.f/1024.f) - mean * mean;
  float rs = rsqrtf(var + 1e-6f);
#pragma unroll
  for (int e = 0; e < 4; ++e){
    int idx = t + (e << 8);
    float y = (v[e] - mean) * rs * w[idx] + bsh[idx];
    out[base + idx] = bf2f(x2[base + idx]) + y;
  }
}

// ---------------- MFMA GEMM: C[M,N] = A[M,K](bf16) * Bt[N,K]^T(bf16) (+fp32 bias/res, gelu) ----------------
// 128x128 tile, BK=32, 4 waves, DEPTH=2 LDS pipeline, counted vmcnt (never 0 in loop).
// CONV: fused 3x3-pad1 im2col addressing in A-staging. OUTB epilogue: C tile staged to LDS
// then stored with 256B-coalesced uint4 writes. XCD-aware bijective block swizzle (T1/m204).
template<int DEPTH, bool BIAS, bool GELU, bool RES, bool OUTB, bool OUTF, bool CONV>
__global__ __launch_bounds__(256, 2) void k_gemm(
    const u16* __restrict__ A, const u16* __restrict__ Bt,
    const float* __restrict__ bias, const float* __restrict__ resf,
    u16* __restrict__ outb, float* __restrict__ outf,
    const u16* __restrict__ zb, int N, int K)
{
  __shared__ __align__(16) u16 smem[DEPTH * 2 * 128 * 32];   // DEPTH=2: 32KB; also C-tile (16384 u16)
  u16* Asb = smem;                     // As[buf] = Asb + buf*4096
  u16* Bsb = smem + DEPTH * 4096;      // Bs[buf] = Bsb + buf*4096
  int t = threadIdx.x, lane = t & 63, wv = t >> 6;

  int nbx = gridDim.x;
  int nwg = nbx * gridDim.y;
  int li  = blockIdx.y * nbx + blockIdx.x;
  int qc = nwg >> 3, rc = nwg & 7;
  int xcd = li & 7, jj = li >> 3;
  int wg = (xcd < rc ? xcd * (qc + 1) : rc * (qc + 1) + (xcd - rc) * qc) + jj;
  int byy = wg / nbx;
  int bxx = wg - byy * nbx;
  int m0 = byy << 7, n0 = bxx << 7;

  int wm = (wv >> 1) << 6, wn = (wv & 1) << 6;

  f32x4 acc[4][4];
  const f32x4 z4 = {0.f, 0.f, 0.f, 0.f};
#pragma unroll
  for (int i = 0; i < 4; ++i)
#pragma unroll
    for (int j = 0; j < 4; ++j) acc[i][j] = z4;

  int srow = (wv << 5) + (lane >> 2);
  int skp  = (lane & 3) << 3;
  const u16* Ag = A  + (size_t)(m0 + srow) * K + skp;
  const u16* Bg = Bt + (size_t)(n0 + srow) * K + skp;
  const size_t rowskip = (size_t)16 * K;

  // CONV per-lane im2col decode for staged rows p0=m0+srow and p1=p0+16
  int bb0 = 0, h0 = 0, w0 = 0, bb1 = 0, h1 = 0, w1 = 0;
  if (CONV){
    int p0 = m0 + srow;
    bb0 = p0 / 784; int s0i = p0 - bb0 * 784; h0 = s0i / 28; w0 = s0i - h0 * 28;
    int p1 = p0 + 16;
    bb1 = p1 / 784; int s1i = p1 - bb1 * 784; h1 = s1i / 28; w1 = s1i - h1 * 28;
  }

  int fr = lane & 15, fq = (lane >> 4) << 3;

  auto stage = [&](int buf, int k0){
    u16* a0 = Asb + buf * 4096 + (wv << 5) * 32;
    u16* b0 = Bsb + buf * 4096 + (wv << 5) * 32;
    if (CONV){
      int tap = k0 >> 9;                       // 0..8, wave-uniform
      int ky = tap / 3, kx = tap - ky * 3;
      int ci = (k0 & 511) + skp;
      int hh0 = h0 + ky - 1, ww0 = w0 + kx - 1;
      int hh1 = h1 + ky - 1, ww1 = w1 + kx - 1;
      const u16* s0 = ((unsigned)hh0 < 28u && (unsigned)ww0 < 28u)
          ? A + (((size_t)(bb0 * 28 + hh0)) * 28 + ww0) * 512 + ci : zb;
      const u16* s1 = ((unsigned)hh1 < 28u && (unsigned)ww1 < 28u)
          ? A + (((size_t)(bb1 * 28 + hh1)) * 28 + ww1) * 512 + ci : zb;
      gld16(s0, a0);
      gld16(s1, a0 + 16 * 32);
    } else {
      gld16(Ag + k0, a0);
      gld16(Ag + rowskip + k0, a0 + 16 * 32);
    }
    gld16(Bg + k0, b0);
    gld16(Bg + rowskip + k0, b0 + 16 * 32);
  };

  auto compute = [&](int buf){
    const u16* As = Asb + buf * 4096;
    const u16* Bs = Bsb + buf * 4096;
    bf16x8 af[4], bfr[4];
#pragma unroll
    for (int i = 0; i < 4; ++i)
      af[i] = *(const bf16x8*)&As[(wm + i * 16 + fr) * 32 + fq];
#pragma unroll
    for (int j = 0; j < 4; ++j)
      bfr[j] = *(const bf16x8*)&Bs[(wn + j * 16 + fr) * 32 + fq];
#pragma unroll
    for (int i = 0; i < 4; ++i)
#pragma unroll
      for (int j = 0; j < 4; ++j)
        acc[i][j] = __builtin_amdgcn_mfma_f32_16x16x32_bf16(af[i], bfr[j], acc[i][j], 0, 0, 0);
  };

  int nk = K >> 5;
  stage(0, 0);                       // prologue: one tile in flight

  for (int kk = 0; kk < nk; ++kk){
    int nxt = kk + 1;
    if (nxt < nk){
      stage(nxt & 1, nxt << 5);
      asm volatile("s_waitcnt vmcnt(4)" ::: "memory");   // tile kk landed; next stays in flight
    } else {
      asm volatile("s_waitcnt vmcnt(0)" ::: "memory");
    }
    __builtin_amdgcn_s_barrier();                        // all waves' tile-kk stores visible
    compute(kk & 1);
    // ds_reads drained via MFMA data-deps before this barrier; buffer kk&1 is only
    // re-staged (as tile kk+2) after all waves pass it.
    __builtin_amdgcn_s_barrier();
  }

  int rr = (lane >> 4) << 2;
  int cc = lane & 15;
  if (OUTB){
    // pass 1: full epilogue math (unchanged), staged to LDS C-tile (reuses As/Bs)
    u16* Cs = smem;
#pragma unroll
    for (int i = 0; i < 4; ++i)
#pragma unroll
      for (int j = 0; j < 4; ++j){
        int lc = wn + j * 16 + cc;
        int gc = n0 + lc;
        float bb = BIAS ? bias[gc] : 0.f;
#pragma unroll
        for (int r = 0; r < 4; ++r){
          int lr = wm + i * 16 + rr + r;
          float vv = acc[i][j][r] + bb;
          if (RES) vv += resf[(size_t)(m0 + lr) * N + gc];
          if (GELU) vv = gelu_f(vv);
          Cs[lr * 128 + lc] = f2bf(vv);
        }
      }
    __syncthreads();
    // pass 2: linear 256B-coalesced stores (16B per lane, consecutive within a row)
#pragma unroll
    for (int it = 0; it < 8; ++it){
      int flat = it * 256 + t;            // 2048 chunks of 8 u16
      int row = flat >> 4;
      int col = (flat & 15) << 3;
      *(uint4*)&outb[(size_t)(m0 + row) * N + n0 + col] = *(const uint4*)&Cs[row * 128 + col];
    }
  } else {
    // OUTF (fp32) path: direct stores (proj only)
#pragma unroll
    for (int i = 0; i < 4; ++i)
#pragma unroll
      for (int j = 0; j < 4; ++j){
        int gc = n0 + wn + j * 16 + cc;
        float bb = BIAS ? bias[gc] : 0.f;
#pragma unroll
        for (int r = 0; r < 4; ++r){
          int gr = m0 + wm + i * 16 + rr + r;
          size_t idx = (size_t)gr * N + gc;
          float vv = acc[i][j][r] + bb;
          if (RES) vv += resf[idx];
          if (GELU) vv = gelu_f(vv);
          outf[idx] = vv;
        }
      }
  }
}

// ---------------- V pre-transpose: qkvbuf V slice -> vtg[bnh][64 d][832 j] (bf16, j zero-padded) ----------------
__global__ __launch_bounds__(256) void k_vtrans(const u16* __restrict__ qkv, u16* __restrict__ vtg){
  __shared__ u32 tile[64][33];
  int bnh = blockIdx.x;            // 0..127
  int st  = blockIdx.y;            // 0..12
  int b = bnh >> 4, nh = bnh & 15;
  int t = threadIdx.x;
  int tx = t & 31;                 // dword column (2 u16)
  int ty = t >> 5;                 // 0..7
  const u16* src = qkv + (size_t)b * 784 * 3072 + 2048 + nh * 64;
  int s0 = st << 6;
  for (int r = ty; r < 64; r += 8){
    int s = s0 + r;
    u32 val = 0u;
    if (s < 784) val = *(const u32*)(src + (size_t)s * 3072 + tx * 2);
    tile[r][tx] = val;
  }
  __syncthreads();
  u16* dst = vtg + (size_t)bnh * 64 * 832 + s0;
  for (int d = ty; d < 64; d += 8){
    u32 lo = tile[2 * tx][d >> 1];
    u32 hi = tile[2 * tx + 1][d >> 1];
    u16 a  = (d & 1) ? (u16)(lo >> 16) : (u16)lo;
    u16 bb = (d & 1) ? (u16)(hi >> 16) : (u16)hi;
    u32 pk = (u32)a | ((u32)bb << 16);
    *(u32*)(dst + (size_t)d * 832 + 2 * tx) = pk;
  }
}

// ---------------- MFMA flash attention v8: double-buffered K/V (counted vmcnt) + coalesced O ----------------
#define PST 72
#define GT2 36
#define LOG2E 1.4426950408889634f
__global__ __launch_bounds__(256, 2) void k_attn8(const u16* __restrict__ qkv,
    const float* __restrict__ relh, const float* __restrict__ relw,
    const u16* __restrict__ vtg, u16* __restrict__ out)
{
  __shared__ __align__(16) u16 k_s[2][64 * 64];     // 16 KB, swizzled K tiles (dbuf); O-tile after loop
  __shared__ __align__(16) u16 v_s[2][64 * 64];     // 16 KB, swizzled V^T tiles (dbuf)
  __shared__ __align__(16) u16 p_s[128 * PST];      // 18 KB, P; also Rh/Rw staging
  __shared__ __align__(16) u16 gh_t[28 * GT2];      // 2 KB, transposed bias (x log2e)
  __shared__ __align__(16) u16 gw_t[28 * GT2];      // 2 KB

  const int t = threadIdx.x, lane = t & 63, wv = t >> 6;
  int id = blockIdx.x;
  int xr = id & 7, rest = id >> 3;
  int qt = rest % 7, gg = rest / 7;
  int bnh = xr + (gg << 3);
  const int b = bnh >> 4, nh = bnh & 15;
  const int q0 = qt << 7;
  const size_t rowbase = (size_t)b * 784;
  const int wq0 = wv << 5;
  const int fr = lane & 15;
  const int fq = lane >> 4;

  // stage Rh/Rw (bf16) into p_s region
  u16* rh_s = p_s;
  u16* rw_s = p_s + 64 * PST;
  {
    int row = t >> 2, c0 = (t & 3) << 4;
    u16 bh_[16], bw_[16];
    if (row < 55){
      const float* ph = relh + row * 64 + c0;
      const float* pw = relw + row * 64 + c0;
#pragma unroll
      for (int e = 0; e < 16; ++e){ bh_[e] = f2bf(ph[e]); bw_[e] = f2bf(pw[e]); }
    } else {
#pragma unroll
      for (int e = 0; e < 16; ++e){ bh_[e] = 0; bw_[e] = 0; }
    }
    *(uint4*)&rh_s[row * PST + c0]     = *(uint4*)bh_;
    *(uint4*)&rh_s[row * PST + c0 + 8] = *(uint4*)(bh_ + 8);
    *(uint4*)&rw_s[row * PST + c0]     = *(uint4*)bw_;
    *(uint4*)&rw_s[row * PST + c0 + 8] = *(uint4*)(bw_ + 8);
  }

  // Q fragments (registers)
  bf16x8 qf[2][2];
#pragma unroll
  for (int mf = 0; mf < 2; ++mf)
#pragma unroll
    for (int ks = 0; ks < 2; ++ks){
      int row = q0 + wq0 + mf * 16 + fr;
      if (row < 784){
        qf[mf][ks] = *(const bf16x8*)(qkv + (rowbase + row) * 3072 + nh * 64 + fq * 8 + ks * 32);
      } else {
        uint4 z = {0u,0u,0u,0u}; qf[mf][ks] = *(bf16x8*)&z;
      }
    }
  __syncthreads();

  const f32x4 z4 = {0.f,0.f,0.f,0.f};
  // ---- decomposed rel-pos bias via MFMA -> transposed tables gt[kk][lr], pre-scaled by log2e ----
#pragma unroll
  for (int which = 0; which < 2; ++which){
    const u16* rs = which ? rw_s : rh_s;
    f32x4 G[2][4];
#pragma unroll
    for (int mf = 0; mf < 2; ++mf)
#pragma unroll
      for (int nf = 0; nf < 4; ++nf) G[mf][nf] = z4;
#pragma unroll
    for (int nf = 0; nf < 4; ++nf){
      bf16x8 rf0 = *(const bf16x8*)&rs[(nf * 16 + fr) * PST + fq * 8];
      bf16x8 rf1 = *(const bf16x8*)&rs[(nf * 16 + fr) * PST + fq * 8 + 32];
#pragma unroll
      for (int mf = 0; mf < 2; ++mf){
        G[mf][nf] = __builtin_amdgcn_mfma_f32_16x16x32_bf16(qf[mf][0], rf0, G[mf][nf], 0, 0, 0);
        G[mf][nf] = __builtin_amdgcn_mfma_f32_16x16x32_bf16(qf[mf][1], rf1, G[mf][nf], 0, 0, 0);
      }
    }
    u16* gt = which ? gw_t : gh_t;
#pragma unroll
    for (int mf = 0; mf < 2; ++mf)
#pragma unroll
      for (int r = 0; r < 4; ++r){
        int lr = wq0 + mf * 16 + fq * 4 + r;
        int grow = q0 + lr;
        int hq = grow / 28;
        int coord = which ? (grow - hq * 28) : hq;
#pragma unroll
        for (int nf = 0; nf < 4; ++nf){
          int j = nf * 16 + fr;
          int kk = coord + 27 - j;
          if ((unsigned)kk < 28u) gt[kk * GT2 + lr] = f2bf(G[mf][nf][r] * LOG2E);
        }
      }
  }

  f32x4 acc[2][5];
#pragma unroll
  for (int mf = 0; mf < 2; ++mf)
#pragma unroll
    for (int nf = 0; nf < 5; ++nf) acc[mf][nf] = z4;

  u16 onesu[8];
#pragma unroll
  for (int e = 0; e < 8; ++e) onesu[e] = 0x3f80;
  bf16x8 onesf = *(bf16x8*)onesu;

  // staging decomposition: lane -> (sub-row sr, swizzled 16B slot sc)
  const int sr = lane >> 3;                 // 0..7
  const int sc = (lane & 7) ^ sr;           // pre-swizzled source slot (involution)
  const u16* kstage = qkv + rowbase * 3072 + 1024 + nh * 64;       // + row*3072 + sc*8
  const u16* vstage = vtg + (size_t)bnh * 64 * 832;                // + d*832 + ktb + sc*8
  const int r0 = (wv << 4) + sr;            // this wave stages rows [wv*16, wv*16+16)
  const int swz = (fr & 7);                 // fragment-read swizzle key

  auto stageKV = [&](int buf, int kt){
    int ktb = kt << 6;
    int jg0 = ktb + r0;       int jc0 = jg0 < 784 ? jg0 : 783;
    int jg1 = jg0 + 8;        int jc1 = jg1 < 784 ? jg1 : 783;
    u16* kd = &k_s[buf][(wv << 4) * 64];
    u16* vd = &v_s[buf][(wv << 4) * 64];
    gld16(kstage + (size_t)jc0 * 3072 + (sc << 3), kd);
    gld16(kstage + (size_t)jc1 * 3072 + (sc << 3), kd + 8 * 64);
    gld16(vstage + (size_t)r0 * 832 + ktb + (sc << 3), vd);
    gld16(vstage + (size_t)(r0 + 8) * 832 + ktb + (sc << 3), vd + 8 * 64);
  };

  // prologue: issue tile 0 staging, then make bias tables visible (raw barrier:
  // ds-writes drained via lgkmcnt; staged vmem stays in flight)
  stageKV(0, 0);
  asm volatile("s_waitcnt lgkmcnt(0)" ::: "memory");
  __builtin_amdgcn_s_barrier();

  const float SSC = 0.125f * LOG2E;

  for (int kt = 0; kt < 13; ++kt){
    if (kt < 12){
      stageKV((kt + 1) & 1, kt + 1);
      asm volatile("s_waitcnt vmcnt(4)" ::: "memory");   // tile kt landed; kt+1 stays in flight
    } else {
      asm volatile("s_waitcnt vmcnt(0)" ::: "memory");
    }
    __builtin_amdgcn_s_barrier();                        // tile kt visible to all waves

    const u16* ks = k_s[kt & 1];
    const u16* vs = v_s[kt & 1];
    const int ktb = kt << 6;

    // QK^T from swizzled LDS
    f32x4 S[2][4];
#pragma unroll
    for (int nf = 0; nf < 4; ++nf){
      int rb = (nf * 16 + fr) << 6;
      bf16x8 kf0 = *(const bf16x8*)&ks[rb + ((fq ^ swz) << 3)];
      bf16x8 kf1 = *(const bf16x8*)&ks[rb + (((fq + 4) ^ swz) << 3)];
#pragma unroll
      for (int mf = 0; mf < 2; ++mf){
        f32x4 s = z4;
        s = __builtin_amdgcn_mfma_f32_16x16x32_bf16(qf[mf][0], kf0, s, 0, 0, 0);
        s = __builtin_amdgcn_mfma_f32_16x16x32_bf16(qf[mf][1], kf1, s, 0, 0, 0);
        S[mf][nf] = s;
      }
    }

    int hj[4], wj[4]; bool val[4];
#pragma unroll
    for (int nf = 0; nf < 4; ++nf){
      int jg = ktb + nf * 16 + fr;
      int h = jg / 28;
      hj[nf] = h; wj[nf] = jg - h * 28; val[nf] = (jg < 784);
    }

    // p = exp2(SSC*S + bias2); bias via b64 reads of transposed tables
#pragma unroll
    for (int mf = 0; mf < 2; ++mf){
      int lrb = wq0 + mf * 16 + fq * 4;
#pragma unroll
      for (int nf = 0; nf < 4; ++nf){
        u16x4 h4 = *(const u16x4*)&gh_t[hj[nf] * GT2 + lrb];
        u16x4 w4 = *(const u16x4*)&gw_t[wj[nf] * GT2 + lrb];
#pragma unroll
        for (int r = 0; r < 4; ++r){
          float p = 0.f;
          if (val[nf])
            p = exp2f(fmaf(SSC, S[mf][nf][r], bf2f(h4[r]) + bf2f(w4[r])));
          p_s[(lrb + r) * PST + nf * 16 + fr] = f2bf(p);
        }
      }
    }

    // PV: P from wave-private LDS rows, V^T fragments from swizzled LDS
#pragma unroll
    for (int ks2 = 0; ks2 < 2; ++ks2){
      bf16x8 pf0 = *(const bf16x8*)&p_s[(wq0 + fr) * PST + fq * 8 + ks2 * 32];
      bf16x8 pf1 = *(const bf16x8*)&p_s[(wq0 + 16 + fr) * PST + fq * 8 + ks2 * 32];
#pragma unroll
      for (int nf = 0; nf < 4; ++nf){
        bf16x8 vf = *(const bf16x8*)&vs[((nf * 16 + fr) << 6) + (((fq + ks2 * 4) ^ swz) << 3)];
        acc[0][nf] = __builtin_amdgcn_mfma_f32_16x16x32_bf16(pf0, vf, acc[0][nf], 0, 0, 0);
        acc[1][nf] = __builtin_amdgcn_mfma_f32_16x16x32_bf16(pf1, vf, acc[1][nf], 0, 0, 0);
      }
      acc[0][4] = __builtin_amdgcn_mfma_f32_16x16x32_bf16(pf0, onesf, acc[0][4], 0, 0, 0);
      acc[1][4] = __builtin_amdgcn_mfma_f32_16x16x32_bf16(pf1, onesf, acc[1][4], 0, 0, 0);
    }
    __builtin_amdgcn_s_barrier();     // all waves done with tile kt before its buffer is re-staged
  }

  // ---- O epilogue: stage to LDS (k_s region, 128x64 u16 = 16KB) then coalesced store ----
  u16* Os = &k_s[0][0];
#pragma unroll
  for (int mf = 0; mf < 2; ++mf)
#pragma unroll
    for (int r = 0; r < 4; ++r){
      int lr = wq0 + mf * 16 + fq * 4 + r;
      float inv = 1.f / acc[mf][4][r];   // ones-fragment: every column holds the row sum
#pragma unroll
      for (int nf = 0; nf < 4; ++nf)
        Os[lr * 64 + nf * 16 + fr] = f2bf(acc[mf][nf][r] * inv);
    }
  __syncthreads();
#pragma unroll
  for (int it = 0; it < 4; ++it){
    int flat = it * 256 + t;            // 1024 chunks of 8 u16
    int row = flat >> 3;
    int col = (flat & 7) << 3;
    int grow = q0 + row;
    if (grow < 784)
      *(uint4*)&out[(rowbase + grow) * 1024 + nh * 64 + col] = *(const uint4*)&Os[row * 64 + col];
  }
}

// ---------------- orchestration ----------------
extern "C" void kernel_launch(void* const* d_in, const int* in_sizes, int n_in,
                              void* d_out, int out_size, void* d_ws, size_t ws_size,
                              hipStream_t stream)
{
  (void)in_sizes; (void)n_in; (void)out_size; (void)ws_size;
  const float* x      = (const float*)d_in[0];
  const float* n1w    = (const float*)d_in[1];
  const float* n1b    = (const float*)d_in[2];
  const float* qkv_w  = (const float*)d_in[3];
  const float* qkv_b  = (const float*)d_in[4];
  const float* proj_w = (const float*)d_in[5];
  const float* proj_b = (const float*)d_in[6];
  const float* rel_h  = (const float*)d_in[7];
  const float* rel_w  = (const float*)d_in[8];
  const float* n2w    = (const float*)d_in[9];
  const float* n2b    = (const float*)d_in[10];
  const float* fc1_w  = (const float*)d_in[11];
  const float* fc1_b  = (const float*)d_in[12];
  const float* fc2_w  = (const float*)d_in[13];
  const float* fc2_b  = (const float*)d_in[14];
  const float* c1w    = (const float*)d_in[15];
  const float* l1w    = (const float*)d_in[16];
  const float* l1b    = (const float*)d_in[17];
  const float* c2w    = (const float*)d_in[18];
  const float* l2w    = (const float*)d_in[19];
  const float* l2b    = (const float*)d_in[20];
  const float* c3w    = (const float*)d_in[21];
  const float* l3w    = (const float*)d_in[22];
  const float* l3b    = (const float*)d_in[23];

  char* ws = (char*)d_ws;
  size_t off = 0;
  auto alloc = [&](size_t bytes) -> void* {
    void* p = ws + off; off += (bytes + 255) & ~(size_t)255; return p;
  };
  const size_t M = 6272;
  u16* qkvT  = (u16*)alloc((size_t)3072 * 1024 * 2);
  u16* projT = (u16*)alloc((size_t)1024 * 1024 * 2);
  u16* fc1T  = (u16*)alloc((size_t)4096 * 1024 * 2);
  u16* fc2T  = (u16*)alloc((size_t)1024 * 4096 * 2);
  u16* c1T   = (u16*)alloc((size_t)512 * 1024 * 2);
  u16* c2T   = (u16*)alloc((size_t)512 * 4608 * 2);
  u16* c3T   = (u16*)alloc((size_t)1024 * 512 * 2);
  u16* qkvbuf = (u16*)alloc(M * 3072 * 2);
  u16* attn   = (u16*)alloc(M * 1024 * 2);
  u16* xn     = (u16*)alloc(M * 1024 * 2);
  float* x1   = (float*)alloc(M * 1024 * 4);
  u16* x2b    = (u16*)alloc(M * 1024 * 2);
  u16* c1buf  = (u16*)alloc(M * 512 * 2);
  u16* g1buf  = (u16*)alloc(M * 512 * 2);
  u16* zbuf   = (u16*)alloc(256);
  u16* hmlp   = qkvbuf;
  u16* xn2    = xn;
  u16* c2buf  = c1buf;
  u16* g2buf  = g1buf;
  u16* c3buf  = attn;
  // vtg (13.6 MB) aliases x1 (25.7 MB): x1 is dead until the proj GEMM, which runs after attn.
  u16* vtg    = (u16*)x1;

  hipMemsetAsync(zbuf, 0, 256, stream);   // zero source for conv-padding staging

  dim3 blk(256);
  k_transpose<<<dim3(3072/32, 1024/32), blk, 0, stream>>>(qkv_w, qkvT, 1024, 3072);
  k_transpose<<<dim3(1024/32, 1024/32), blk, 0, stream>>>(proj_w, projT, 1024, 1024);
  k_transpose<<<dim3(4096/32, 1024/32), blk, 0, stream>>>(fc1_w, fc1T, 1024, 4096);
  k_transpose<<<dim3(1024/32, 4096/32), blk, 0, stream>>>(fc2_w, fc2T, 4096, 1024);
  k_transpose<<<dim3(512/32, 1024/32),  blk, 0, stream>>>(c1w, c1T, 1024, 512);
  k_transpose<<<dim3(512/32, 4608/32),  blk, 0, stream>>>(c2w, c2T, 4608, 512);
  k_transpose<<<dim3(1024/32, 512/32),  blk, 0, stream>>>(c3w, c3T, 512, 1024);

  k_layernorm<true,false><<<6272, blk, 0, stream>>>(x, n1w, n1b, xn, 1024, 1e-5f);
  k_gemm<2,true,false,false,true,false,false><<<dim3(24,49), blk, 0, stream>>>(
      xn, qkvT, qkv_b, nullptr, qkvbuf, nullptr, nullptr, 3072, 1024);
  k_vtrans<<<dim3(128, 13), blk, 0, stream>>>(qkvbuf, vtg);
  k_attn8<<<896, blk, 0, stream>>>(qkvbuf, rel_h, rel_w, vtg, attn);
  k_gemm<2,true,false,true,false,true,false><<<dim3(8,49), blk, 0, stream>>>(
      attn, projT, proj_b, x, nullptr, x1, nullptr, 1024, 1024);
  k_layernorm<true,false><<<6272, blk, 0, stream>>>(x1, n2w, n2b, xn2, 1024, 1e-5f);
  k_gemm<2,true,true,false,true,false,false><<<dim3(32,49), blk, 0, stream>>>(
      xn2, fc1T, fc1_b, nullptr, hmlp, nullptr, nullptr, 4096, 1024);
  k_gemm<2,true,false,true,true,false,false><<<dim3(8,49), blk, 0, stream>>>(
      hmlp, fc2T, fc2_b, x1, x2b, nullptr, nullptr, 1024, 4096);
  k_gemm<2,false,false,false,true,false,false><<<dim3(4,49), blk, 0, stream>>>(
      x2b, c1T, nullptr, nullptr, c1buf, nullptr, nullptr, 512, 1024);
  k_layernorm<false,true><<<6272, blk, 0, stream>>>(c1buf, l1w, l1b, g1buf, 512, 1e-6f);
  // c2: fused im2col conv GEMM (A = g1buf, 3x3 pad-1 addressing in staging)
  k_gemm<2,false,false,false,true,false,true><<<dim3(4,49), blk, 0, stream>>>(
      g1buf, c2T, nullptr, nullptr, c2buf, nullptr, zbuf, 512, 4608);
  k_layernorm<false,true><<<6272, blk, 0, stream>>>(c2buf, l2w, l2b, g2buf, 512, 1e-6f);
  k_gemm<2,false,false,false,true,false,false><<<dim3(8,49), blk, 0, stream>>>(
      g2buf, c3T, nullptr, nullptr, c3buf, nullptr, nullptr, 1024, 512);
  k_final<<<6272, blk, 0, stream>>>(c3buf, x2b, l3w, l3b, (float*)d_out);
}

// Round 13
// 656.199 us; speedup vs baseline: 1.1232x; 1.0145x over previous
//
#include <hip/hip_runtime.h>
#include <cstdint>
#include <cstddef>

using u16 = unsigned short;
using u32 = unsigned int;

// ---------------- helpers ----------------
__device__ __forceinline__ float bf2f(u16 u){
  union { u32 i; float f; } x; x.i = ((u32)u) << 16; return x.f;
}
__device__ __forceinline__ u16 f2bf(float f){
  union { float f; u32 i; } x; x.f = f;
  u32 r = x.i + 0x7fffu + ((x.i >> 16) & 1u);
  return (u16)(r >> 16);
}
__device__ __forceinline__ float gelu_f(float x){
  return 0.5f * x * (1.0f + erff(x * 0.70710678118654752f));
}
__device__ __forceinline__ void gld16(const void* g, void* l){
  // async global->LDS, 16B/lane; LDS dst = wave-uniform base + lane*16; global src per-lane
  __builtin_amdgcn_global_load_lds((__attribute__((address_space(1))) void*)(void*)g,
                                   (__attribute__((address_space(3))) void*)l, 16, 0, 0);
}

typedef __bf16 bf16x8 __attribute__((ext_vector_type(8)));
typedef float  f32x4  __attribute__((ext_vector_type(4)));
typedef u16    u16x4  __attribute__((ext_vector_type(4)));

// ---------------- merged weight transpose + cast: 7 fp32 [R,C] -> bf16 [C,R] in one launch ----------------
struct TSeg { const float* src; u16* dst; int R; int C; int tx; int start; };
struct TSegs { TSeg s[7]; };

__global__ __launch_bounds__(256) void k_transpose_all(TSegs segs){
  __shared__ u16 tile[32][33];
  int bid = blockIdx.x;
  const float* src = segs.s[0].src; u16* dst = segs.s[0].dst;
  int R = segs.s[0].R, C = segs.s[0].C, tx = segs.s[0].tx, loc = bid;
#pragma unroll
  for (int i = 1; i < 7; ++i){
    if (bid >= segs.s[i].start){
      src = segs.s[i].src; dst = segs.s[i].dst;
      R = segs.s[i].R; C = segs.s[i].C; tx = segs.s[i].tx;
      loc = bid - segs.s[i].start;
    }
  }
  int byt = loc / tx, bxt = loc - byt * tx;
  int bx = bxt << 5, by = byt << 5;
  int txi = threadIdx.x & 31;
  int ty  = threadIdx.x >> 5;
  for (int r = ty; r < 32; r += 8)
    tile[r][txi] = f2bf(src[(size_t)(by + r) * C + bx + txi]);
  __syncthreads();
  for (int r = ty; r < 32; r += 8)
    dst[(size_t)(bx + r) * R + by + txi] = tile[txi][r];
}

// ---------------- layernorm over last dim (cols = 1024 or 512), optional gelu, bf16 out ----------------
template<bool IN_F32, bool DO_GELU>
__global__ __launch_bounds__(256) void k_layernorm(const void* __restrict__ inp,
    const float* __restrict__ w, const float* __restrict__ bsh,
    u16* __restrict__ out, int cols, float eps){
  int row = blockIdx.x, t = threadIdx.x;
  size_t base = (size_t)row * cols;
  const float* inf = (const float*)inp;
  const u16*  inb = (const u16*)inp;
  float v[4];
  int ep = cols >> 8;
  float s = 0.f, ss = 0.f;
  for (int e = 0; e < ep; ++e){
    int idx = t + (e << 8);
    float x = IN_F32 ? inf[base + idx] : bf2f(inb[base + idx]);
    v[e] = x; s += x; ss += x * x;
  }
#pragma unroll
  for (int off = 1; off < 64; off <<= 1){
    s  += __shfl_xor(s, off, 64);
    ss += __shfl_xor(ss, off, 64);
  }
  __shared__ float red[8];
  int wv = t >> 6;
  if ((t & 63) == 0){ red[wv] = s; red[4 + wv] = ss; }
  __syncthreads();
  s  = red[0] + red[1] + red[2] + red[3];
  ss = red[4] + red[5] + red[6] + red[7];
  float inv = 1.f / (float)cols;
  float mean = s * inv;
  float var = ss * inv - mean * mean;
  float rs = rsqrtf(var + eps);
  for (int e = 0; e < ep; ++e){
    int idx = t + (e << 8);
    float y = (v[e] - mean) * rs * w[idx] + bsh[idx];
    if (DO_GELU) y = gelu_f(y);
    out[base + idx] = f2bf(y);
  }
}

// ---------------- final: out(fp32) = x2(bf16) + LN(c3; ln3) , cols=1024 ----------------
__global__ __launch_bounds__(256) void k_final(const u16* __restrict__ c3,
    const u16* __restrict__ x2, const float* __restrict__ w,
    const float* __restrict__ bsh, float* __restrict__ out){
  int row = blockIdx.x, t = threadIdx.x;
  size_t base = (size_t)row << 10;
  float v[4];
  float s = 0.f, ss = 0.f;
#pragma unroll
  for (int e = 0; e < 4; ++e){
    int idx = t + (e << 8);
    float x = bf2f(c3[base + idx]);
    v[e] = x; s += x; ss += x * x;
  }
#pragma unroll
  for (int off = 1; off < 64; off <<= 1){
    s  += __shfl_xor(s, off, 64);
    ss += __shfl_xor(ss, off, 64);
  }
  __shared__ float red[8];
  int wv = t >> 6;
  if ((t & 63) == 0){ red[wv] = s; red[4 + wv] = ss; }
  __syncthreads();
  s  = red[0] + red[1] + red[2] + red[3];
  ss = red[4] + red[5] + red[6] + red[7];
  float mean = s * (1.f/1024.f);
  float var = ss * (1.f/1024.f) - mean * mean;
  float rs = rsqrtf(var + 1e-6f);
#pragma unroll
  for (int e = 0; e < 4; ++e){
    int idx = t + (e << 8);
    float y = (v[e] - mean) * rs * w[idx] + bsh[idx];
    out[base + idx] = bf2f(x2[base + idx]) + y;
  }
}

// ---------------- MFMA GEMM: C[M,N] = A[M,K](bf16) * Bt[N,K]^T(bf16) (+fp32 bias/res, gelu) ----------------
// 128x128 tile, BK=32, 4 waves, DEPTH=2 LDS pipeline, counted vmcnt (never 0 in loop).
// Rasterization: GROUP_M=8 super-grouping (B-panel reused 8x consecutively) composed with
// the XCD-aware bijective chunk map (T1/m204) for per-XCD L2 locality.
// CONV: fused 3x3-pad1 im2col addressing in A-staging. OUTB epilogue: C tile staged to LDS
// then stored with 256B-coalesced uint4 writes.
template<int DEPTH, bool BIAS, bool GELU, bool RES, bool OUTB, bool OUTF, bool CONV>
__global__ __launch_bounds__(256, 2) void k_gemm(
    const u16* __restrict__ A, const u16* __restrict__ Bt,
    const float* __restrict__ bias, const float* __restrict__ resf,
    u16* __restrict__ outb, float* __restrict__ outf,
    const u16* __restrict__ zb, int N, int K)
{
  __shared__ __align__(16) u16 smem[DEPTH * 2 * 128 * 32];   // DEPTH=2: 32KB; also C-tile (16384 u16)
  u16* Asb = smem;                     // As[buf] = Asb + buf*4096
  u16* Bsb = smem + DEPTH * 4096;      // Bs[buf] = Bsb + buf*4096
  int t = threadIdx.x, lane = t & 63, wv = t >> 6;

  int nbx = gridDim.x;
  int nby = gridDim.y;
  int nwg = nbx * nby;
  int li  = blockIdx.y * nbx + blockIdx.x;
  // XCD-aware bijective chunking
  int qc = nwg >> 3, rc = nwg & 7;
  int xcd = li & 7, jj = li >> 3;
  int wg = (xcd < rc ? xcd * (qc + 1) : rc * (qc + 1) + (xcd - rc) * qc) + jj;
  // GROUP_M=8 rasterization: within each 8-row super-group, walk column-major
  int wpg = nbx << 3;
  int g   = wg / wpg;
  int r8  = wg - g * wpg;
  int rows = nby - (g << 3); rows = rows < 8 ? rows : 8;
  int bxx = r8 / rows;
  int byy = (g << 3) + (r8 - bxx * rows);
  int m0 = byy << 7, n0 = bxx << 7;

  int wm = (wv >> 1) << 6, wn = (wv & 1) << 6;

  f32x4 acc[4][4];
  const f32x4 z4 = {0.f, 0.f, 0.f, 0.f};
#pragma unroll
  for (int i = 0; i < 4; ++i)
#pragma unroll
    for (int j = 0; j < 4; ++j) acc[i][j] = z4;

  int srow = (wv << 5) + (lane >> 2);
  int skp  = (lane & 3) << 3;
  const u16* Ag = A  + (size_t)(m0 + srow) * K + skp;
  const u16* Bg = Bt + (size_t)(n0 + srow) * K + skp;
  const size_t rowskip = (size_t)16 * K;

  // CONV per-lane im2col decode for staged rows p0=m0+srow and p1=p0+16
  int bb0 = 0, h0 = 0, w0 = 0, bb1 = 0, h1 = 0, w1 = 0;
  if (CONV){
    int p0 = m0 + srow;
    bb0 = p0 / 784; int s0i = p0 - bb0 * 784; h0 = s0i / 28; w0 = s0i - h0 * 28;
    int p1 = p0 + 16;
    bb1 = p1 / 784; int s1i = p1 - bb1 * 784; h1 = s1i / 28; w1 = s1i - h1 * 28;
  }

  int fr = lane & 15, fq = (lane >> 4) << 3;

  auto stage = [&](int buf, int k0){
    u16* a0 = Asb + buf * 4096 + (wv << 5) * 32;
    u16* b0 = Bsb + buf * 4096 + (wv << 5) * 32;
    if (CONV){
      int tap = k0 >> 9;                       // 0..8, wave-uniform
      int ky = tap / 3, kx = tap - ky * 3;
      int ci = (k0 & 511) + skp;
      int hh0 = h0 + ky - 1, ww0 = w0 + kx - 1;
      int hh1 = h1 + ky - 1, ww1 = w1 + kx - 1;
      const u16* s0 = ((unsigned)hh0 < 28u && (unsigned)ww0 < 28u)
          ? A + (((size_t)(bb0 * 28 + hh0)) * 28 + ww0) * 512 + ci : zb;
      const u16* s1 = ((unsigned)hh1 < 28u && (unsigned)ww1 < 28u)
          ? A + (((size_t)(bb1 * 28 + hh1)) * 28 + ww1) * 512 + ci : zb;
      gld16(s0, a0);
      gld16(s1, a0 + 16 * 32);
    } else {
      gld16(Ag + k0, a0);
      gld16(Ag + rowskip + k0, a0 + 16 * 32);
    }
    gld16(Bg + k0, b0);
    gld16(Bg + rowskip + k0, b0 + 16 * 32);
  };

  auto compute = [&](int buf){
    const u16* As = Asb + buf * 4096;
    const u16* Bs = Bsb + buf * 4096;
    bf16x8 af[4], bfr[4];
#pragma unroll
    for (int i = 0; i < 4; ++i)
      af[i] = *(const bf16x8*)&As[(wm + i * 16 + fr) * 32 + fq];
#pragma unroll
    for (int j = 0; j < 4; ++j)
      bfr[j] = *(const bf16x8*)&Bs[(wn + j * 16 + fr) * 32 + fq];
#pragma unroll
    for (int i = 0; i < 4; ++i)
#pragma unroll
      for (int j = 0; j < 4; ++j)
        acc[i][j] = __builtin_amdgcn_mfma_f32_16x16x32_bf16(af[i], bfr[j], acc[i][j], 0, 0, 0);
  };

  int nk = K >> 5;
  stage(0, 0);                       // prologue: one tile in flight

  for (int kk = 0; kk < nk; ++kk){
    int nxt = kk + 1;
    if (nxt < nk){
      stage(nxt & 1, nxt << 5);
      asm volatile("s_waitcnt vmcnt(4)" ::: "memory");   // tile kk landed; next stays in flight
    } else {
      asm volatile("s_waitcnt vmcnt(0)" ::: "memory");
    }
    __builtin_amdgcn_s_barrier();                        // all waves' tile-kk stores visible
    compute(kk & 1);
    // ds_reads drained via MFMA data-deps before this barrier; buffer kk&1 is only
    // re-staged (as tile kk+2) after all waves pass it.
    __builtin_amdgcn_s_barrier();
  }

  int rr = (lane >> 4) << 2;
  int cc = lane & 15;
  if (OUTB){
    // pass 1: full epilogue math (unchanged), staged to LDS C-tile (reuses As/Bs)
    u16* Cs = smem;
#pragma unroll
    for (int i = 0; i < 4; ++i)
#pragma unroll
      for (int j = 0; j < 4; ++j){
        int lc = wn + j * 16 + cc;
        int gc = n0 + lc;
        float bb = BIAS ? bias[gc] : 0.f;
#pragma unroll
        for (int r = 0; r < 4; ++r){
          int lr = wm + i * 16 + rr + r;
          float vv = acc[i][j][r] + bb;
          if (RES) vv += resf[(size_t)(m0 + lr) * N + gc];
          if (GELU) vv = gelu_f(vv);
          Cs[lr * 128 + lc] = f2bf(vv);
        }
      }
    __syncthreads();
    // pass 2: linear 256B-coalesced stores (16B per lane, consecutive within a row)
#pragma unroll
    for (int it = 0; it < 8; ++it){
      int flat = it * 256 + t;            // 2048 chunks of 8 u16
      int row = flat >> 4;
      int col = (flat & 15) << 3;
      *(uint4*)&outb[(size_t)(m0 + row) * N + n0 + col] = *(const uint4*)&Cs[row * 128 + col];
    }
  } else {
    // OUTF (fp32) path: direct stores (proj only)
#pragma unroll
    for (int i = 0; i < 4; ++i)
#pragma unroll
      for (int j = 0; j < 4; ++j){
        int gc = n0 + wn + j * 16 + cc;
        float bb = BIAS ? bias[gc] : 0.f;
#pragma unroll
        for (int r = 0; r < 4; ++r){
          int gr = m0 + wm + i * 16 + rr + r;
          size_t idx = (size_t)gr * N + gc;
          float vv = acc[i][j][r] + bb;
          if (RES) vv += resf[idx];
          if (GELU) vv = gelu_f(vv);
          outf[idx] = vv;
        }
      }
  }
}

// ---------------- V pre-transpose: qkvbuf V slice -> vtg[bnh][64 d][832 j] (bf16, j zero-padded) ----------------
__global__ __launch_bounds__(256) void k_vtrans(const u16* __restrict__ qkv, u16* __restrict__ vtg){
  __shared__ u32 tile[64][33];
  int bnh = blockIdx.x;            // 0..127
  int st  = blockIdx.y;            // 0..12
  int b = bnh >> 4, nh = bnh & 15;
  int t = threadIdx.x;
  int tx = t & 31;                 // dword column (2 u16)
  int ty = t >> 5;                 // 0..7
  const u16* src = qkv + (size_t)b * 784 * 3072 + 2048 + nh * 64;
  int s0 = st << 6;
  for (int r = ty; r < 64; r += 8){
    int s = s0 + r;
    u32 val = 0u;
    if (s < 784) val = *(const u32*)(src + (size_t)s * 3072 + tx * 2);
    tile[r][tx] = val;
  }
  __syncthreads();
  u16* dst = vtg + (size_t)bnh * 64 * 832 + s0;
  for (int d = ty; d < 64; d += 8){
    u32 lo = tile[2 * tx][d >> 1];
    u32 hi = tile[2 * tx + 1][d >> 1];
    u16 a  = (d & 1) ? (u16)(lo >> 16) : (u16)lo;
    u16 bb = (d & 1) ? (u16)(hi >> 16) : (u16)hi;
    u32 pk = (u32)a | ((u32)bb << 16);
    *(u32*)(dst + (size_t)d * 832 + 2 * tx) = pk;
  }
}

// ---------------- MFMA flash attention v8: double-buffered K/V (counted vmcnt) + coalesced O ----------------
#define PST 72
#define GT2 36
#define LOG2E 1.4426950408889634f
__global__ __launch_bounds__(256, 2) void k_attn8(const u16* __restrict__ qkv,
    const float* __restrict__ relh, const float* __restrict__ relw,
    const u16* __restrict__ vtg, u16* __restrict__ out)
{
  __shared__ __align__(16) u16 k_s[2][64 * 64];     // 16 KB, swizzled K tiles (dbuf); O-tile after loop
  __shared__ __align__(16) u16 v_s[2][64 * 64];     // 16 KB, swizzled V^T tiles (dbuf)
  __shared__ __align__(16) u16 p_s[128 * PST];      // 18 KB, P; also Rh/Rw staging
  __shared__ __align__(16) u16 gh_t[28 * GT2];      // 2 KB, transposed bias (x log2e)
  __shared__ __align__(16) u16 gw_t[28 * GT2];      // 2 KB

  const int t = threadIdx.x, lane = t & 63, wv = t >> 6;
  int id = blockIdx.x;
  int xr = id & 7, rest = id >> 3;
  int qt = rest % 7, gg = rest / 7;
  int bnh = xr + (gg << 3);
  const int b = bnh >> 4, nh = bnh & 15;
  const int q0 = qt << 7;
  const size_t rowbase = (size_t)b * 784;
  const int wq0 = wv << 5;
  const int fr = lane & 15;
  const int fq = lane >> 4;

  // stage Rh/Rw (bf16) into p_s region
  u16* rh_s = p_s;
  u16* rw_s = p_s + 64 * PST;
  {
    int row = t >> 2, c0 = (t & 3) << 4;
    u16 bh_[16], bw_[16];
    if (row < 55){
      const float* ph = relh + row * 64 + c0;
      const float* pw = relw + row * 64 + c0;
#pragma unroll
      for (int e = 0; e < 16; ++e){ bh_[e] = f2bf(ph[e]); bw_[e] = f2bf(pw[e]); }
    } else {
#pragma unroll
      for (int e = 0; e < 16; ++e){ bh_[e] = 0; bw_[e] = 0; }
    }
    *(uint4*)&rh_s[row * PST + c0]     = *(uint4*)bh_;
    *(uint4*)&rh_s[row * PST + c0 + 8] = *(uint4*)(bh_ + 8);
    *(uint4*)&rw_s[row * PST + c0]     = *(uint4*)bw_;
    *(uint4*)&rw_s[row * PST + c0 + 8] = *(uint4*)(bw_ + 8);
  }

  // Q fragments (registers)
  bf16x8 qf[2][2];
#pragma unroll
  for (int mf = 0; mf < 2; ++mf)
#pragma unroll
    for (int ks = 0; ks < 2; ++ks){
      int row = q0 + wq0 + mf * 16 + fr;
      if (row < 784){
        qf[mf][ks] = *(const bf16x8*)(qkv + (rowbase + row) * 3072 + nh * 64 + fq * 8 + ks * 32);
      } else {
        uint4 z = {0u,0u,0u,0u}; qf[mf][ks] = *(bf16x8*)&z;
      }
    }
  __syncthreads();

  const f32x4 z4 = {0.f,0.f,0.f,0.f};
  // ---- decomposed rel-pos bias via MFMA -> transposed tables gt[kk][lr], pre-scaled by log2e ----
#pragma unroll
  for (int which = 0; which < 2; ++which){
    const u16* rs = which ? rw_s : rh_s;
    f32x4 G[2][4];
#pragma unroll
    for (int mf = 0; mf < 2; ++mf)
#pragma unroll
      for (int nf = 0; nf < 4; ++nf) G[mf][nf] = z4;
#pragma unroll
    for (int nf = 0; nf < 4; ++nf){
      bf16x8 rf0 = *(const bf16x8*)&rs[(nf * 16 + fr) * PST + fq * 8];
      bf16x8 rf1 = *(const bf16x8*)&rs[(nf * 16 + fr) * PST + fq * 8 + 32];
#pragma unroll
      for (int mf = 0; mf < 2; ++mf){
        G[mf][nf] = __builtin_amdgcn_mfma_f32_16x16x32_bf16(qf[mf][0], rf0, G[mf][nf], 0, 0, 0);
        G[mf][nf] = __builtin_amdgcn_mfma_f32_16x16x32_bf16(qf[mf][1], rf1, G[mf][nf], 0, 0, 0);
      }
    }
    u16* gt = which ? gw_t : gh_t;
#pragma unroll
    for (int mf = 0; mf < 2; ++mf)
#pragma unroll
      for (int r = 0; r < 4; ++r){
        int lr = wq0 + mf * 16 + fq * 4 + r;
        int grow = q0 + lr;
        int hq = grow / 28;
        int coord = which ? (grow - hq * 28) : hq;
#pragma unroll
        for (int nf = 0; nf < 4; ++nf){
          int j = nf * 16 + fr;
          int kk = coord + 27 - j;
          if ((unsigned)kk < 28u) gt[kk * GT2 + lr] = f2bf(G[mf][nf][r] * LOG2E);
        }
      }
  }

  f32x4 acc[2][5];
#pragma unroll
  for (int mf = 0; mf < 2; ++mf)
#pragma unroll
    for (int nf = 0; nf < 5; ++nf) acc[mf][nf] = z4;

  u16 onesu[8];
#pragma unroll
  for (int e = 0; e < 8; ++e) onesu[e] = 0x3f80;
  bf16x8 onesf = *(bf16x8*)onesu;

  // staging decomposition: lane -> (sub-row sr, swizzled 16B slot sc)
  const int sr = lane >> 3;                 // 0..7
  const int sc = (lane & 7) ^ sr;           // pre-swizzled source slot (involution)
  const u16* kstage = qkv + rowbase * 3072 + 1024 + nh * 64;       // + row*3072 + sc*8
  const u16* vstage = vtg + (size_t)bnh * 64 * 832;                // + d*832 + ktb + sc*8
  const int r0 = (wv << 4) + sr;            // this wave stages rows [wv*16, wv*16+16)
  const int swz = (fr & 7);                 // fragment-read swizzle key

  auto stageKV = [&](int buf, int kt){
    int ktb = kt << 6;
    int jg0 = ktb + r0;       int jc0 = jg0 < 784 ? jg0 : 783;
    int jg1 = jg0 + 8;        int jc1 = jg1 < 784 ? jg1 : 783;
    u16* kd = &k_s[buf][(wv << 4) * 64];
    u16* vd = &v_s[buf][(wv << 4) * 64];
    gld16(kstage + (size_t)jc0 * 3072 + (sc << 3), kd);
    gld16(kstage + (size_t)jc1 * 3072 + (sc << 3), kd + 8 * 64);
    gld16(vstage + (size_t)r0 * 832 + ktb + (sc << 3), vd);
    gld16(vstage + (size_t)(r0 + 8) * 832 + ktb + (sc << 3), vd + 8 * 64);
  };

  // prologue: issue tile 0 staging, then make bias tables visible (raw barrier:
  // ds-writes drained via lgkmcnt; staged vmem stays in flight)
  stageKV(0, 0);
  asm volatile("s_waitcnt lgkmcnt(0)" ::: "memory");
  __builtin_amdgcn_s_barrier();

  const float SSC = 0.125f * LOG2E;

  for (int kt = 0; kt < 13; ++kt){
    if (kt < 12){
      stageKV((kt + 1) & 1, kt + 1);
      asm volatile("s_waitcnt vmcnt(4)" ::: "memory");   // tile kt landed; kt+1 stays in flight
    } else {
      asm volatile("s_waitcnt vmcnt(0)" ::: "memory");
    }
    __builtin_amdgcn_s_barrier();                        // tile kt visible to all waves

    const u16* ks = k_s[kt & 1];
    const u16* vs = v_s[kt & 1];
    const int ktb = kt << 6;

    // QK^T from swizzled LDS
    f32x4 S[2][4];
#pragma unroll
    for (int nf = 0; nf < 4; ++nf){
      int rb = (nf * 16 + fr) << 6;
      bf16x8 kf0 = *(const bf16x8*)&ks[rb + ((fq ^ swz) << 3)];
      bf16x8 kf1 = *(const bf16x8*)&ks[rb + (((fq + 4) ^ swz) << 3)];
#pragma unroll
      for (int mf = 0; mf < 2; ++mf){
        f32x4 s = z4;
        s = __builtin_amdgcn_mfma_f32_16x16x32_bf16(qf[mf][0], kf0, s, 0, 0, 0);
        s = __builtin_amdgcn_mfma_f32_16x16x32_bf16(qf[mf][1], kf1, s, 0, 0, 0);
        S[mf][nf] = s;
      }
    }

    int hj[4], wj[4]; bool val[4];
#pragma unroll
    for (int nf = 0; nf < 4; ++nf){
      int jg = ktb + nf * 16 + fr;
      int h = jg / 28;
      hj[nf] = h; wj[nf] = jg - h * 28; val[nf] = (jg < 784);
    }

    // p = exp2(SSC*S + bias2); bias via b64 reads of transposed tables
#pragma unroll
    for (int mf = 0; mf < 2; ++mf){
      int lrb = wq0 + mf * 16 + fq * 4;
#pragma unroll
      for (int nf = 0; nf < 4; ++nf){
        u16x4 h4 = *(const u16x4*)&gh_t[hj[nf] * GT2 + lrb];
        u16x4 w4 = *(const u16x4*)&gw_t[wj[nf] * GT2 + lrb];
#pragma unroll
        for (int r = 0; r < 4; ++r){
          float p = 0.f;
          if (val[nf])
            p = exp2f(fmaf(SSC, S[mf][nf][r], bf2f(h4[r]) + bf2f(w4[r])));
          p_s[(lrb + r) * PST + nf * 16 + fr] = f2bf(p);
        }
      }
    }

    // PV: P from wave-private LDS rows, V^T fragments from swizzled LDS
#pragma unroll
    for (int ks2 = 0; ks2 < 2; ++ks2){
      bf16x8 pf0 = *(const bf16x8*)&p_s[(wq0 + fr) * PST + fq * 8 + ks2 * 32];
      bf16x8 pf1 = *(const bf16x8*)&p_s[(wq0 + 16 + fr) * PST + fq * 8 + ks2 * 32];
#pragma unroll
      for (int nf = 0; nf < 4; ++nf){
        bf16x8 vf = *(const bf16x8*)&vs[((nf * 16 + fr) << 6) + (((fq + ks2 * 4) ^ swz) << 3)];
        acc[0][nf] = __builtin_amdgcn_mfma_f32_16x16x32_bf16(pf0, vf, acc[0][nf], 0, 0, 0);
        acc[1][nf] = __builtin_amdgcn_mfma_f32_16x16x32_bf16(pf1, vf, acc[1][nf], 0, 0, 0);
      }
      acc[0][4] = __builtin_amdgcn_mfma_f32_16x16x32_bf16(pf0, onesf, acc[0][4], 0, 0, 0);
      acc[1][4] = __builtin_amdgcn_mfma_f32_16x16x32_bf16(pf1, onesf, acc[1][4], 0, 0, 0);
    }
    __builtin_amdgcn_s_barrier();     // all waves done with tile kt before its buffer is re-staged
  }

  // ---- O epilogue: stage to LDS (k_s region, 128x64 u16 = 16KB) then coalesced store ----
  u16* Os = &k_s[0][0];
#pragma unroll
  for (int mf = 0; mf < 2; ++mf)
#pragma unroll
    for (int r = 0; r < 4; ++r){
      int lr = wq0 + mf * 16 + fq * 4 + r;
      float inv = 1.f / acc[mf][4][r];   // ones-fragment: every column holds the row sum
#pragma unroll
      for (int nf = 0; nf < 4; ++nf)
        Os[lr * 64 + nf * 16 + fr] = f2bf(acc[mf][nf][r] * inv);
    }
  __syncthreads();
#pragma unroll
  for (int it = 0; it < 4; ++it){
    int flat = it * 256 + t;            // 1024 chunks of 8 u16
    int row = flat >> 3;
    int col = (flat & 7) << 3;
    int grow = q0 + row;
    if (grow < 784)
      *(uint4*)&out[(rowbase + grow) * 1024 + nh * 64 + col] = *(const uint4*)&Os[row * 64 + col];
  }
}

// ---------------- orchestration ----------------
extern "C" void kernel_launch(void* const* d_in, const int* in_sizes, int n_in,
                              void* d_out, int out_size, void* d_ws, size_t ws_size,
                              hipStream_t stream)
{
  (void)in_sizes; (void)n_in; (void)out_size; (void)ws_size;
  const float* x      = (const float*)d_in[0];
  const float* n1w    = (const float*)d_in[1];
  const float* n1b    = (const float*)d_in[2];
  const float* qkv_w  = (const float*)d_in[3];
  const float* qkv_b  = (const float*)d_in[4];
  const float* proj_w = (const float*)d_in[5];
  const float* proj_b = (const float*)d_in[6];
  const float* rel_h  = (const float*)d_in[7];
  const float* rel_w  = (const float*)d_in[8];
  const float* n2w    = (const float*)d_in[9];
  const float* n2b    = (const float*)d_in[10];
  const float* fc1_w  = (const float*)d_in[11];
  const float* fc1_b  = (const float*)d_in[12];
  const float* fc2_w  = (const float*)d_in[13];
  const float* fc2_b  = (const float*)d_in[14];
  const float* c1w    = (const float*)d_in[15];
  const float* l1w    = (const float*)d_in[16];
  const float* l1b    = (const float*)d_in[17];
  const float* c2w    = (const float*)d_in[18];
  const float* l2w    = (const float*)d_in[19];
  const float* l2b    = (const float*)d_in[20];
  const float* c3w    = (const float*)d_in[21];
  const float* l3w    = (const float*)d_in[22];
  const float* l3b    = (const float*)d_in[23];

  char* ws = (char*)d_ws;
  size_t off = 0;
  auto alloc = [&](size_t bytes) -> void* {
    void* p = ws + off; off += (bytes + 255) & ~(size_t)255; return p;
  };
  const size_t M = 6272;
  u16* qkvT  = (u16*)alloc((size_t)3072 * 1024 * 2);
  u16* projT = (u16*)alloc((size_t)1024 * 1024 * 2);
  u16* fc1T  = (u16*)alloc((size_t)4096 * 1024 * 2);
  u16* fc2T  = (u16*)alloc((size_t)1024 * 4096 * 2);
  u16* c1T   = (u16*)alloc((size_t)512 * 1024 * 2);
  u16* c2T   = (u16*)alloc((size_t)512 * 4608 * 2);
  u16* c3T   = (u16*)alloc((size_t)1024 * 512 * 2);
  u16* qkvbuf = (u16*)alloc(M * 3072 * 2);
  u16* attn   = (u16*)alloc(M * 1024 * 2);
  u16* xn     = (u16*)alloc(M * 1024 * 2);
  float* x1   = (float*)alloc(M * 1024 * 4);
  u16* x2b    = (u16*)alloc(M * 1024 * 2);
  u16* c1buf  = (u16*)alloc(M * 512 * 2);
  u16* g1buf  = (u16*)alloc(M * 512 * 2);
  u16* zbuf   = (u16*)alloc(256);
  u16* hmlp   = qkvbuf;
  u16* xn2    = xn;
  u16* c2buf  = c1buf;
  u16* g2buf  = g1buf;
  u16* c3buf  = attn;
  // vtg (13.6 MB) aliases x1 (25.7 MB): x1 is dead until the proj GEMM, which runs after attn.
  u16* vtg    = (u16*)x1;

  hipMemsetAsync(zbuf, 0, 256, stream);   // zero source for conv-padding staging

  dim3 blk(256);
  // merged weight transposes: one launch, 7 segments
  TSegs segs;
  int tstart = 0;
  auto addseg = [&](int i, const float* s, u16* d, int R, int C){
    segs.s[i] = TSeg{ s, d, R, C, C >> 5, tstart };
    tstart += (C >> 5) * (R >> 5);
  };
  addseg(0, qkv_w, qkvT, 1024, 3072);
  addseg(1, proj_w, projT, 1024, 1024);
  addseg(2, fc1_w, fc1T, 1024, 4096);
  addseg(3, fc2_w, fc2T, 4096, 1024);
  addseg(4, c1w, c1T, 1024, 512);
  addseg(5, c2w, c2T, 4608, 512);
  addseg(6, c3w, c3T, 512, 1024);
  k_transpose_all<<<tstart, blk, 0, stream>>>(segs);

  k_layernorm<true,false><<<6272, blk, 0, stream>>>(x, n1w, n1b, xn, 1024, 1e-5f);
  k_gemm<2,true,false,false,true,false,false><<<dim3(24,49), blk, 0, stream>>>(
      xn, qkvT, qkv_b, nullptr, qkvbuf, nullptr, nullptr, 3072, 1024);
  k_vtrans<<<dim3(128, 13), blk, 0, stream>>>(qkvbuf, vtg);
  k_attn8<<<896, blk, 0, stream>>>(qkvbuf, rel_h, rel_w, vtg, attn);
  k_gemm<2,true,false,true,false,true,false><<<dim3(8,49), blk, 0, stream>>>(
      attn, projT, proj_b, x, nullptr, x1, nullptr, 1024, 1024);
  k_layernorm<true,false><<<6272, blk, 0, stream>>>(x1, n2w, n2b, xn2, 1024, 1e-5f);
  k_gemm<2,true,true,false,true,false,false><<<dim3(32,49), blk, 0, stream>>>(
      xn2, fc1T, fc1_b, nullptr, hmlp, nullptr, nullptr, 4096, 1024);
  k_gemm<2,true,false,true,true,false,false><<<dim3(8,49), blk, 0, stream>>>(
      hmlp, fc2T, fc2_b, x1, x2b, nullptr, nullptr, 1024, 4096);
  k_gemm<2,false,false,false,true,false,false><<<dim3(4,49), blk, 0, stream>>>(
      x2b, c1T, nullptr, nullptr, c1buf, nullptr, nullptr, 512, 1024);
  k_layernorm<false,true><<<6272, blk, 0, stream>>>(c1buf, l1w, l1b, g1buf, 512, 1e-6f);
  // c2: fused im2col conv GEMM (A = g1buf, 3x3 pad-1 addressing in staging)
  k_gemm<2,false,false,false,true,false,true><<<dim3(4,49), blk, 0, stream>>>(
      g1buf, c2T, nullptr, nullptr, c2buf, nullptr, zbuf, 512, 4608);
  k_layernorm<false,true><<<6272, blk, 0, stream>>>(c2buf, l2w, l2b, g2buf, 512, 1e-6f);
  k_gemm<2,false,false,false,true,false,false><<<dim3(8,49), blk, 0, stream>>>(
      g2buf, c3T, nullptr, nullptr, c3buf, nullptr, nullptr, 1024, 512);
  k_final<<<6272, blk, 0, stream>>>(c3buf, x2b, l3w, l3b, (float*)d_out);
}